// Round 1
// baseline (1578.995 us; speedup 1.0000x reference)
//
#include <hip/hip_runtime.h>
#include <math.h>

#define T_LEN 8192
#define KK 64
#define DD 128
#define RS 132
#define NTERM 7

__device__ __forceinline__ float wred_max(float v){
#pragma unroll
  for (int m = 1; m < 64; m <<= 1) v = fmaxf(v, __shfl_xor(v, m, 64));
  return v;
}
__device__ __forceinline__ float wred_sum(float v){
#pragma unroll
  for (int m = 1; m < 64; m <<= 1) v += __shfl_xor(v, m, 64);
  return v;
}
__device__ __forceinline__ float digamma_f(float x){
  float r = 0.f;
  while (x < 6.f){ r -= 1.f/x; x += 1.f; }
  float ix = 1.f/x, ix2 = ix*ix;
  return r + logf(x) - 0.5f*ix - ix2*(0.0833333333f - ix2*(0.0083333333f - ix2*0.0039682540f));
}

// ---------------- ElogA, P, PT ----------------
__global__ void k_elog(const float* __restrict__ phi, float* __restrict__ ElogA,
                       float* __restrict__ P, float* __restrict__ PT){
  int i = blockIdx.x, j = threadIdx.x;
  float ph = phi[i*KK + j];
  float s  = wred_sum(ph);
  float e  = digamma_f(ph) - digamma_f(s);
  ElogA[i*KK + j] = e;
  float p = expf(e);
  P [i*KK + j] = p;
  PT[j*KK + i] = p;
}

// ---------------- Neumann inverse + logdet + digamma sums (one block per k) ----------------
__global__ void __launch_bounds__(256) k_neumann(
    const float* __restrict__ Psi, const float* __restrict__ niw_mu,
    const float* __restrict__ nu_,
    float* __restrict__ ELamT, float* __restrict__ EdiagT,
    float* __restrict__ cvecT, float* __restrict__ rK, float* __restrict__ Lhalf)
{
  extern __shared__ float lds[];
  float* Rl = lds;            // [DD][RS]
  float* Pb = lds + DD*RS;    // [DD][RS]
  __shared__ float red[256];
  __shared__ float msh[DD];
  int k = blockIdx.x, tid = threadIdx.x;
  const float* A = Psi + (size_t)k*DD*DD;

  // c = trace/D
  float tl = 0.f;
  for (int d = tid; d < DD; d += 256) tl += A[d*DD + d];
  red[tid] = tl; __syncthreads();
  for (int off = 128; off > 0; off >>= 1){ if (tid < off) red[tid] += red[tid+off]; __syncthreads(); }
  float c = red[0] / (float)DD;
  __syncthreads();

  // R = I - Psi/c ; Pb = R ; accumulate tr(R)
  float trpow = 0.f;
  for (int idx = tid; idx < DD*DD; idx += 256){
    int d = idx >> 7, e = idx & 127;
    float v = ((d == e) ? 1.f : 0.f) - A[idx]/c;
    Rl[d*RS + e] = v; Pb[d*RS + e] = v;
    if (d == e) trpow += v;          // n=1 term
  }
  __syncthreads();

  int tr = tid >> 4, tc = tid & 15;
  int r0 = tr*8, c0 = tc*8;
  float S[8][8];
#pragma unroll
  for (int i = 0; i < 8; i++)
#pragma unroll
    for (int j = 0; j < 8; j++){
      float v = Rl[(r0+i)*RS + c0+j];
      if (r0+i == c0+j) v += 1.f;
      S[i][j] = v;                    // S = I + R
    }

  for (int n = 2; n <= NTERM; n++){
    float Cc[8][8];
#pragma unroll
    for (int i = 0; i < 8; i++)
#pragma unroll
      for (int j = 0; j < 8; j++) Cc[i][j] = 0.f;
    for (int l = 0; l < DD; l += 4){
      float af[4][8], bf[4][8];
#pragma unroll
      for (int q = 0; q < 4; q++){
        // R symmetric: R[r][l+q] = R[l+q][r]
        float4 x0 = *(const float4*)&Rl[(l+q)*RS + r0];
        float4 x1 = *(const float4*)&Rl[(l+q)*RS + r0 + 4];
        af[q][0]=x0.x; af[q][1]=x0.y; af[q][2]=x0.z; af[q][3]=x0.w;
        af[q][4]=x1.x; af[q][5]=x1.y; af[q][6]=x1.z; af[q][7]=x1.w;
        float4 y0 = *(const float4*)&Pb[(l+q)*RS + c0];
        float4 y1 = *(const float4*)&Pb[(l+q)*RS + c0 + 4];
        bf[q][0]=y0.x; bf[q][1]=y0.y; bf[q][2]=y0.z; bf[q][3]=y0.w;
        bf[q][4]=y1.x; bf[q][5]=y1.y; bf[q][6]=y1.z; bf[q][7]=y1.w;
      }
#pragma unroll
      for (int q = 0; q < 4; q++)
#pragma unroll
        for (int i = 0; i < 8; i++)
#pragma unroll
          for (int j = 0; j < 8; j++)
            Cc[i][j] = fmaf(af[q][i], bf[q][j], Cc[i][j]);
    }
    __syncthreads();
#pragma unroll
    for (int i = 0; i < 8; i++){
      float4 w0, w1;
      w0.x=Cc[i][0]; w0.y=Cc[i][1]; w0.z=Cc[i][2]; w0.w=Cc[i][3];
      w1.x=Cc[i][4]; w1.y=Cc[i][5]; w1.z=Cc[i][6]; w1.w=Cc[i][7];
      *(float4*)&Pb[(r0+i)*RS + c0]     = w0;
      *(float4*)&Pb[(r0+i)*RS + c0 + 4] = w1;
    }
    __syncthreads();
    float fn = 1.f/(float)n;
#pragma unroll
    for (int i = 0; i < 8; i++)
#pragma unroll
      for (int j = 0; j < 8; j++) S[i][j] += Cc[i][j];
    if (tr == tc){
#pragma unroll
      for (int i = 0; i < 8; i++) trpow += Cc[i][i]*fn;
    }
  }

  // reduce trace-sum
  red[tid] = trpow; __syncthreads();
  for (int off = 128; off > 0; off >>= 1){ if (tid < off) red[tid] += red[tid+off]; __syncthreads(); }
  float trsum = red[0];
  __syncthreads();

  float nu = nu_[k];
  float dl = 0.f;
  for (int i = tid; i < DD; i += 256) dl += digamma_f((nu - (float)i)*0.5f); // (nu+1-(i+1))/2
  red[tid] = dl; __syncthreads();
  for (int off = 128; off > 0; off >>= 1){ if (tid < off) red[tid] += red[tid+off]; __syncthreads(); }
  if (tid == 0){
    float logdetPsi = (float)DD*logf(c) - trsum;
    float Elogdet = red[0] + (float)DD*0.69314718056f - logdetPsi;
    Lhalf[k] = 0.5f*Elogdet - 0.5f*(float)DD*1.83787706641f; // -0.5 D ln(2pi)
  }
  __syncthreads();

  float scl = nu / c;
#pragma unroll
  for (int i = 0; i < 8; i++)
#pragma unroll
    for (int j = 0; j < 8; j++){
      float el = scl * S[i][j];
      ELamT[(size_t)((r0+i)*DD + c0+j)*KK + k] = el;
      if (r0+i == c0+j) EdiagT[(r0+i)*KK + k] = el;
    }
  // write S into Pb for the cvec row-dots
#pragma unroll
  for (int i = 0; i < 8; i++){
    float4 w0, w1;
    w0.x=S[i][0]; w0.y=S[i][1]; w0.z=S[i][2]; w0.w=S[i][3];
    w1.x=S[i][4]; w1.y=S[i][5]; w1.z=S[i][6]; w1.w=S[i][7];
    *(float4*)&Pb[(r0+i)*RS + c0]     = w0;
    *(float4*)&Pb[(r0+i)*RS + c0 + 4] = w1;
  }
  for (int d = tid; d < DD; d += 256) msh[d] = niw_mu[k*DD + d];
  __syncthreads();
  float cv = 0.f;
  if (tid < DD){
    float acc = 0.f;
    for (int e = 0; e < DD; e++) acc += Pb[tid*RS + e]*msh[e];
    cv = scl*acc;
    cvecT[tid*KK + k] = cv;
  }
  red[tid] = (tid < DD) ? msh[tid]*cv : 0.f; __syncthreads();
  for (int off = 128; off > 0; off >>= 1){ if (tid < off) red[tid] += red[tid+off]; __syncthreads(); }
  if (tid == 0) rK[k] = red[0];
}

// ---------------- q1[t,k] = mu_t^T ELam_k mu_t  (split-K over d,e segments) ----------------
__global__ void __launch_bounds__(256) k_q1(const float* __restrict__ mu,
      const float* __restrict__ ELamT, float* __restrict__ q1)
{
  __shared__ float muT[64*66];   // [e][t]
  __shared__ float wt[16*64];    // [d][t]
  __shared__ float Bd[64*64];    // [e][k]
  int b = blockIdx.x;
  int eseg = b & 1, dseg = (b >> 1) & 7, tseg = b >> 4;
  int t0 = tseg*64, e0 = eseg*64, d0 = dseg*16;
  int tid = threadIdx.x;
  int l = tid & 63, kg = tid >> 6;
  int t = t0 + l, k0 = kg*16;

  for (int v = tid; v < 64*64; v += 256){
    int i = v >> 6, j = v & 63;
    muT[j*66 + i] = mu[(size_t)(t0+i)*DD + e0 + j];
  }
  for (int v = tid; v < 16*64; v += 256){
    int di = v >> 6, i = v & 63;
    wt[di*64 + i] = mu[(size_t)(t0+i)*DD + d0 + di];
  }
  __syncthreads();

  float acc[16];
#pragma unroll
  for (int q = 0; q < 16; q++) acc[q] = 0.f;

  for (int d = 0; d < 16; d++){
    __syncthreads();
    const float4* src = (const float4*)(ELamT + ((size_t)(d0+d)*DD + e0)*KK);
    for (int v = tid; v < 1024; v += 256) ((float4*)Bd)[v] = src[v];
    __syncthreads();
    float w = wt[d*64 + l];
    for (int e = 0; e < 64; e++){
      float a = muT[e*66 + l] * w;
      const float4* bp = (const float4*)(&Bd[e*64 + k0]);
      float4 b0 = bp[0], b1 = bp[1], b2 = bp[2], b3 = bp[3];
      acc[0]=fmaf(a,b0.x,acc[0]); acc[1]=fmaf(a,b0.y,acc[1]); acc[2]=fmaf(a,b0.z,acc[2]); acc[3]=fmaf(a,b0.w,acc[3]);
      acc[4]=fmaf(a,b1.x,acc[4]); acc[5]=fmaf(a,b1.y,acc[5]); acc[6]=fmaf(a,b1.z,acc[6]); acc[7]=fmaf(a,b1.w,acc[7]);
      acc[8]=fmaf(a,b2.x,acc[8]); acc[9]=fmaf(a,b2.y,acc[9]); acc[10]=fmaf(a,b2.z,acc[10]); acc[11]=fmaf(a,b2.w,acc[11]);
      acc[12]=fmaf(a,b3.x,acc[12]); acc[13]=fmaf(a,b3.y,acc[13]); acc[14]=fmaf(a,b3.z,acc[14]); acc[15]=fmaf(a,b3.w,acc[15]);
    }
  }
#pragma unroll
  for (int q = 0; q < 16; q++) atomicAdd(q1 + (size_t)t*KK + k0 + q, acc[q]);
}

// ---------------- finalize logB, rowmax m_t, btil ----------------
__global__ void __launch_bounds__(256) k_logBall(
    const float* __restrict__ q1, const float* __restrict__ mu, const float* __restrict__ dvar,
    const float* __restrict__ cvecT, const float* __restrict__ EdiagT,
    const float* __restrict__ rK, const float* __restrict__ Lhalf,
    float* __restrict__ logB, float* __restrict__ mrow, float* __restrict__ btil)
{
  extern __shared__ float lds[];
  float* cv = lds; float* ed = lds + DD*KK;
  int tid = threadIdx.x; int k = tid & 63; int w = tid >> 6;
  for (int v = tid; v < DD*KK; v += 256){ cv[v] = cvecT[v]; ed[v] = EdiagT[v]; }
  __syncthreads();
  float rk = rK[k], lh = Lhalf[k];
  int tbase = blockIdx.x*64 + w*16;
  for (int ii = 0; ii < 16; ii++){
    int t = tbase + ii;
    const float* murow = mu   + (size_t)t*DD;
    const float* dvrow = dvar + (size_t)t*DD;
    float a1 = 0.f, a2 = 0.f;
    for (int d = 0; d < DD; d++){
      float md = murow[d];
      float vd = fmaxf(dvrow[d], 0.f);
      a1 = fmaf(md, cv[d*KK + k], a1);
      a2 = fmaf(vd, ed[d*KK + k], a2);
    }
    float q  = q1[(size_t)t*KK + k];
    float lb = lh - 0.5f*(q - 2.f*a1 + rk + a2);
    float m  = wred_max(lb);
    logB[(size_t)t*KK + k] = lb;
    btil[(size_t)t*KK + k] = expf(lb - m);
    if (k == 0) mrow[t] = m;
  }
}

// ---------------- pass1: 8-step chunk operators G8 (one wave per chunk) ----------------
#define GROW(r) ((r)*68 + ((((r)>>3)&3)*4))
__global__ void __launch_bounds__(128) k_pass1(const float* __restrict__ Pm,
     const float* __restrict__ btil, float* __restrict__ G8)
{
  __shared__ float lds_s[4352 + 2*4368];
  float* Pl = lds_s;
  int tid = threadIdx.x;
  int w = tid >> 6, lane = tid & 63;
  float* G = lds_s + 4352 + w*4368;
  for (int v = tid; v < 4096; v += 128) Pl[(v>>6)*68 + (v&63)] = Pm[v];
  int chunk = blockIdx.x*2 + w;
  int ti = lane >> 3, tj = lane & 7;
  int r0 = ti*8, c0 = tj*8;
  for (int v = lane; v < 4096; v += 64){
    int i = v >> 6, j = v & 63;
    G[GROW(i) + j] = (i == j) ? 1.f : 0.f;
  }
  __syncthreads();

  for (int s = 0; s < 8; s++){
    int t = chunk*8 + s;
    if (t < 1) continue;           // chunk 0 skips t=0 (wave-uniform)
    float acc[8][8];
#pragma unroll
    for (int i = 0; i < 8; i++)
#pragma unroll
      for (int j = 0; j < 8; j++) acc[i][j] = 0.f;
    for (int l = 0; l < 64; l += 4){
      float af[8][4];
#pragma unroll
      for (int i = 0; i < 8; i++){
        float4 x = *(const float4*)&G[GROW(r0+i) + l];
        af[i][0]=x.x; af[i][1]=x.y; af[i][2]=x.z; af[i][3]=x.w;
      }
      float bf[4][8];
#pragma unroll
      for (int q = 0; q < 4; q++){
        float4 y0 = *(const float4*)&Pl[(l+q)*68 + c0];
        float4 y1 = *(const float4*)&Pl[(l+q)*68 + c0 + 4];
        bf[q][0]=y0.x; bf[q][1]=y0.y; bf[q][2]=y0.z; bf[q][3]=y0.w;
        bf[q][4]=y1.x; bf[q][5]=y1.y; bf[q][6]=y1.z; bf[q][7]=y1.w;
      }
#pragma unroll
      for (int q = 0; q < 4; q++)
#pragma unroll
        for (int i = 0; i < 8; i++)
#pragma unroll
          for (int j = 0; j < 8; j++)
            acc[i][j] = fmaf(af[i][q], bf[q][j], acc[i][j]);
    }
    float4 bb0 = *(const float4*)&btil[(size_t)t*KK + c0];
    float4 bb1 = *(const float4*)&btil[(size_t)t*KK + c0 + 4];
    float bj[8] = {bb0.x,bb0.y,bb0.z,bb0.w,bb1.x,bb1.y,bb1.z,bb1.w};
    float mx = 0.f;
#pragma unroll
    for (int i = 0; i < 8; i++)
#pragma unroll
      for (int j = 0; j < 8; j++){ acc[i][j] *= bj[j]; mx = fmaxf(mx, acc[i][j]); }
    mx = wred_max(mx);
    float inv = 1.f/mx;
#pragma unroll
    for (int i = 0; i < 8; i++){
      float4 w0, w1;
      w0.x=acc[i][0]*inv; w0.y=acc[i][1]*inv; w0.z=acc[i][2]*inv; w0.w=acc[i][3]*inv;
      w1.x=acc[i][4]*inv; w1.y=acc[i][5]*inv; w1.z=acc[i][6]*inv; w1.w=acc[i][7]*inv;
      *(float4*)&G[GROW(r0+i) + c0]     = w0;
      *(float4*)&G[GROW(r0+i) + c0 + 4] = w1;
    }
  }
  float* dst = G8 + (size_t)chunk*4096;
  for (int v = lane; v < 4096; v += 64) dst[v] = G[GROW(v>>6) + (v&63)];
}

// ---------------- chain-combine: dst[c] = prod_{j} src[c*chain+j], store lin+log ----------------
__global__ void __launch_bounds__(256) k_chain(const float* __restrict__ src,
        float* __restrict__ dstLin, float* __restrict__ dstLog, int chain)
{
  __shared__ float X[64*68];
  __shared__ float Y[64*68];
  __shared__ float red[256];
  int cb = blockIdx.x, tid = threadIdx.x;
  const float* s0 = src + (size_t)cb*chain*4096;
  for (int v = tid; v < 4096; v += 256) X[(v>>6)*68 + (v&63)] = s0[v];
  int ti = tid >> 4, tj = tid & 15;
  int r0 = ti*4, c0 = tj*4;
  for (int j = 1; j < chain; j++){
    const float* sj = s0 + (size_t)j*4096;
    for (int v = tid; v < 4096; v += 256) Y[(v>>6)*68 + (v&63)] = sj[v];
    __syncthreads();
    float acc[4][4];
#pragma unroll
    for (int i = 0; i < 4; i++)
#pragma unroll
      for (int q = 0; q < 4; q++) acc[i][q] = 0.f;
    for (int l = 0; l < 64; l++){
      float a0 = X[(r0+0)*68 + l], a1 = X[(r0+1)*68 + l];
      float a2 = X[(r0+2)*68 + l], a3 = X[(r0+3)*68 + l];
      float4 yy = *(const float4*)&Y[l*68 + c0];
      acc[0][0]=fmaf(a0,yy.x,acc[0][0]); acc[0][1]=fmaf(a0,yy.y,acc[0][1]); acc[0][2]=fmaf(a0,yy.z,acc[0][2]); acc[0][3]=fmaf(a0,yy.w,acc[0][3]);
      acc[1][0]=fmaf(a1,yy.x,acc[1][0]); acc[1][1]=fmaf(a1,yy.y,acc[1][1]); acc[1][2]=fmaf(a1,yy.z,acc[1][2]); acc[1][3]=fmaf(a1,yy.w,acc[1][3]);
      acc[2][0]=fmaf(a2,yy.x,acc[2][0]); acc[2][1]=fmaf(a2,yy.y,acc[2][1]); acc[2][2]=fmaf(a2,yy.z,acc[2][2]); acc[2][3]=fmaf(a2,yy.w,acc[2][3]);
      acc[3][0]=fmaf(a3,yy.x,acc[3][0]); acc[3][1]=fmaf(a3,yy.y,acc[3][1]); acc[3][2]=fmaf(a3,yy.z,acc[3][2]); acc[3][3]=fmaf(a3,yy.w,acc[3][3]);
    }
    float mx = 0.f;
#pragma unroll
    for (int i = 0; i < 4; i++)
#pragma unroll
      for (int q = 0; q < 4; q++) mx = fmaxf(mx, acc[i][q]);
    red[tid] = mx; __syncthreads();
    for (int off = 128; off > 0; off >>= 1){ if (tid < off) red[tid] = fmaxf(red[tid], red[tid+off]); __syncthreads(); }
    float inv = 1.f/red[0];
    __syncthreads();
#pragma unroll
    for (int i = 0; i < 4; i++){
      float4 wv; wv.x=acc[i][0]*inv; wv.y=acc[i][1]*inv; wv.z=acc[i][2]*inv; wv.w=acc[i][3]*inv;
      *(float4*)&X[(r0+i)*68 + c0] = wv;
    }
    __syncthreads();
  }
  for (int v = tid; v < 4096; v += 256){
    float vv = X[(v>>6)*68 + (v&63)];
    dstLin[(size_t)cb*4096 + v] = vv;
    dstLog[(size_t)cb*4096 + v] = logf(vv);
  }
}

// ---------------- pass2: sequential scan over 64 128-step log-operators ----------------
__global__ void k_pass2(const float* __restrict__ LH128,
    const float* __restrict__ logB, const float* __restrict__ log_pi,
    float* __restrict__ aB, float* __restrict__ bB)
{
  __shared__ float Hl[64*68];
  __shared__ float vl[64];
  int lane = threadIdx.x;
  if (blockIdx.x == 0){
    float v = log_pi[lane] + logB[lane];
    float m = wred_max(v);
    float la = v - m;
    for (int c = 0; c < 64; c++){
      for (int u = lane; u < 1024; u += 64){
        float4 x = ((const float4*)(LH128 + (size_t)c*4096))[u];
        int row = u >> 4, col = (u & 15)*4;
        *(float4*)&Hl[row*68 + col] = x;
      }
      vl[lane] = la;
      __syncthreads();
      float mx = -3.0e38f;
      for (int i = 0; i < 64; i++) mx = fmaxf(mx, vl[i] + Hl[i*68 + lane]);
      float s = 0.f;
      for (int i = 0; i < 64; i++) s += expf(vl[i] + Hl[i*68 + lane] - mx);
      float ln = mx + logf(s);
      float mm = wred_max(ln);
      la = ln - mm;
      float e  = expf(la);
      float ss = wred_sum(e);
      aB[c*64 + lane] = e/ss;
      __syncthreads();
    }
  } else {
    float lb = 0.f;
    bB[63*64 + lane] = 1.f;
    for (int c = 63; c >= 1; c--){
      for (int u = lane; u < 1024; u += 64){
        float4 x = ((const float4*)(LH128 + (size_t)c*4096))[u];
        int row = u >> 4, col = (u & 15)*4;
        Hl[(col+0)*68 + row] = x.x; Hl[(col+1)*68 + row] = x.y;
        Hl[(col+2)*68 + row] = x.z; Hl[(col+3)*68 + row] = x.w;
      }
      vl[lane] = lb;
      __syncthreads();
      float mx = -3.0e38f;
      for (int j = 0; j < 64; j++) mx = fmaxf(mx, Hl[j*68 + lane] + vl[j]);
      float s = 0.f;
      for (int j = 0; j < 64; j++) s += expf(Hl[j*68 + lane] + vl[j] - mx);
      float ln = mx + logf(s);
      float mm = wred_max(ln);
      lb = ln - mm;
      bB[(c-1)*64 + lane] = expf(lb);
      __syncthreads();
    }
  }
}

// ---------------- pass3: per-64-step-chunk exact recurrences ----------------
__global__ void k_pass3(const float* __restrict__ Pm, const float* __restrict__ PTm,
   const float* __restrict__ LH64,
   const float* __restrict__ logB, const float* __restrict__ mrow, const float* __restrict__ btil,
   const float* __restrict__ log_pi,
   const float* __restrict__ aB, const float* __restrict__ bB,
   float* __restrict__ alphahat, float* __restrict__ betahat, float* __restrict__ llpart)
{
  __shared__ float Hl[64*68];
  __shared__ float vl[64];
  int lane = threadIdx.x;
  int bid = blockIdx.x;
  if (bid < 128){
    int c = bid;
    float Preg[64];
#pragma unroll
    for (int i = 0; i < 64; i++) Preg[i] = Pm[i*64 + lane];
    float a; float llacc = 0.f;
    int tstart;
    if (c == 0){
      float v = log_pi[lane] + logB[lane];
      float m = wred_max(v);
      float e = expf(v - m);
      float s = wred_sum(e);
      a = e/s;
      llacc = m + logf(s);
      alphahat[lane] = a;
      tstart = 1;
    } else if (c & 1){
      float lp;
      if (c == 1){
        float v = log_pi[lane] + logB[lane];
        float m = wred_max(v);
        lp = v - m;
      } else {
        lp = logf(aB[((c-1)/2 - 1)*64 + lane]);
      }
      for (int u = lane; u < 1024; u += 64){
        float4 x = ((const float4*)(LH64 + (size_t)(c-1)*4096))[u];
        int row = u >> 4, col = (u & 15)*4;
        *(float4*)&Hl[row*68 + col] = x;
      }
      vl[lane] = lp;
      __syncthreads();
      float mx = -3.0e38f;
      for (int i = 0; i < 64; i++) mx = fmaxf(mx, vl[i] + Hl[i*68 + lane]);
      float s = 0.f;
      for (int i = 0; i < 64; i++) s += expf(vl[i] + Hl[i*68 + lane] - mx);
      float ln = mx + logf(s);
      float mm = wred_max(ln);
      float e  = expf(ln - mm);
      float ss = wred_sum(e);
      a = e/ss;
      __syncthreads();
      tstart = c*64;
    } else {
      a = aB[(c/2 - 1)*64 + lane];
      tstart = c*64;
    }
    int tend = c*64 + 64;
    for (int t = tstart; t < tend; t++){
      vl[lane] = a;
      __syncthreads();
      float pred = 0.f;
#pragma unroll
      for (int i = 0; i < 64; i++) pred = fmaf(vl[i], Preg[i], pred);
      __syncthreads();
      float at = pred * btil[(size_t)t*KK + lane];
      float s  = wred_sum(at);
      a = at / s;
      llacc += logf(s) + mrow[t];
      alphahat[(size_t)t*KK + lane] = a;
    }
    if (lane == 0) llpart[c] = llacc;
  } else {
    int c = bid - 128;
    float PTreg[64];
#pragma unroll
    for (int j = 0; j < 64; j++) PTreg[j] = PTm[j*64 + lane];
    float b, lb;
    if (c == 127){
      b = 1.f; lb = 0.f;
    } else if (c & 1){
      b = bB[((c-1)/2)*64 + lane];
      lb = logf(b);
    } else {
      float lbin = logf(bB[(c/2)*64 + lane]);
      for (int u = lane; u < 1024; u += 64){
        float4 x = ((const float4*)(LH64 + (size_t)(c+1)*4096))[u];
        int row = u >> 4, col = (u & 15)*4;
        Hl[(col+0)*68 + row] = x.x; Hl[(col+1)*68 + row] = x.y;
        Hl[(col+2)*68 + row] = x.z; Hl[(col+3)*68 + row] = x.w;
      }
      vl[lane] = lbin;
      __syncthreads();
      float mx = -3.0e38f;
      for (int j = 0; j < 64; j++) mx = fmaxf(mx, Hl[j*68 + lane] + vl[j]);
      float s = 0.f;
      for (int j = 0; j < 64; j++) s += expf(Hl[j*68 + lane] + vl[j] - mx);
      float ln = mx + logf(s);
      float mm = wred_max(ln);
      lb = ln - mm;
      b = expf(lb);
      __syncthreads();
    }
    int t1 = c*64 + 63;
    betahat[(size_t)t1*KK + lane] = b;
    for (int t = t1 - 1; t >= c*64; t--){
      float lv = (logB[(size_t)(t+1)*KK + lane] - mrow[t+1]) + lb;
      float vm = wred_max(lv);
      float vv = expf(lv - vm);
      vl[lane] = vv;
      __syncthreads();
      float bn = 0.f;
#pragma unroll
      for (int j = 0; j < 64; j++) bn = fmaf(PTreg[j], vl[j], bn);
      __syncthreads();
      float bmax = wred_max(bn);
      b = bn / bmax;
      lb = logf(b);
      betahat[(size_t)t*KK + lane] = b;
    }
  }
}

// ---------------- outputs ----------------
__global__ void k_out_rhat(const float* __restrict__ ah, const float* __restrict__ bh,
                           float* __restrict__ out){
  int tid = threadIdx.x; int w = tid >> 6, lane = tid & 63;
  int t = blockIdx.x*4 + w;
  float la = logf(ah[(size_t)t*KK + lane]);
  float lb = logf(bh[(size_t)t*KK + lane]);
  float s = la + lb;
  float m = wred_max(s);
  float p = (m < -3.0e37f) ? 1.f : expf(s - m);
  float ss = wred_sum(p);
  out[(size_t)t*KK + lane] = p/ss;
}

__global__ void __launch_bounds__(256) k_out_xi(const float* __restrict__ ah,
     const float* __restrict__ bh, const float* __restrict__ ElogA,
     const float* __restrict__ logB, float* __restrict__ out)
{
  __shared__ float la[64], wc[64];
  __shared__ float red[256];
  int tid = threadIdx.x;
  int t = blockIdx.x + 1;
  if (tid < 64) la[tid] = logf(ah[(size_t)(t-1)*KK + tid]);
  else if (tid < 128){
    int j = tid - 64;
    wc[j] = logB[(size_t)t*KK + j] + logf(bh[(size_t)t*KK + j]);
  }
  __syncthreads();
  int r = tid >> 6, j = tid & 63;
  float sv[16];
  float mx = -3.0e38f;
#pragma unroll
  for (int n = 0; n < 16; n++){
    int i = r + n*4;
    float s = la[i] + ElogA[i*KK + j] + wc[j];
    sv[n] = s;
    mx = fmaxf(mx, s);
  }
  red[tid] = mx; __syncthreads();
  for (int off = 128; off > 0; off >>= 1){ if (tid < off) red[tid] = fmaxf(red[tid], red[tid+off]); __syncthreads(); }
  float m = red[0];
  __syncthreads();
  bool degen = !(m > -3.0e37f);
  float pv[16]; float ps = 0.f;
#pragma unroll
  for (int n = 0; n < 16; n++){
    float p = degen ? 1.f : expf(sv[n] - m);
    pv[n] = p; ps += p;
  }
  red[tid] = ps; __syncthreads();
  for (int off = 128; off > 0; off >>= 1){ if (tid < off) red[tid] += red[tid+off]; __syncthreads(); }
  float inv = 1.f/red[0];
  float* dst = out + (size_t)(t-1)*4096;
#pragma unroll
  for (int n = 0; n < 16; n++){
    int i = r + n*4;
    dst[i*KK + j] = pv[n]*inv;
  }
}

__global__ void k_ll(const float* __restrict__ llpart, float* __restrict__ out){
  __shared__ float red[128];
  int tid = threadIdx.x;
  red[tid] = llpart[tid];
  __syncthreads();
  for (int off = 64; off > 0; off >>= 1){ if (tid < off) red[tid] += red[tid+off]; __syncthreads(); }
  if (tid == 0) out[0] = red[0];
}

extern "C" void kernel_launch(void* const* d_in, const int* in_sizes, int n_in,
                              void* d_out, int out_size, void* d_ws, size_t ws_size,
                              hipStream_t stream)
{
  const float* mu    = (const float*)d_in[0];
  const float* dvar  = (const float*)d_in[1];
  const float* niwmu = (const float*)d_in[2];
  const float* Psi   = (const float*)d_in[3];
  const float* nu    = (const float*)d_in[4];
  const float* phi   = (const float*)d_in[5];
  const float* lpi   = (const float*)d_in[6];
  float* out = (float*)d_out;
  float* ws  = (float*)d_ws;

  size_t o = 0;
  float* ELamT  = ws + o; o += (size_t)DD*DD*KK;
  float* EdiagT = ws + o; o += (size_t)DD*KK;
  float* cvecT  = ws + o; o += (size_t)DD*KK;
  float* rK     = ws + o; o += KK;
  float* Lhalf  = ws + o; o += KK;
  float* ElogA  = ws + o; o += KK*KK;
  float* P      = ws + o; o += KK*KK;
  float* PT     = ws + o; o += KK*KK;
  float* logB   = ws + o; o += (size_t)T_LEN*KK;
  float* mrowp  = ws + o; o += T_LEN;
  float* btil   = ws + o; o += (size_t)T_LEN*KK;
  float* q1     = ws + o; o += (size_t)T_LEN*KK;
  float* G8     = ws + o; o += (size_t)1024*4096;
  float* H64    = ws + o; o += (size_t)128*4096;
  float* LH64   = ws + o; o += (size_t)128*4096;
  float* H128   = ws + o; o += (size_t)64*4096;
  float* LH128  = ws + o; o += (size_t)64*4096;
  float* aB     = ws + o; o += 64*64;
  float* bB     = ws + o; o += 64*64;
  float* llp    = ws + o; o += 128;
  float* ah     = ws + o; o += (size_t)T_LEN*KK;
  float* bh     = ws + o; o += (size_t)T_LEN*KK;
  if (ws_size < o*sizeof(float)) return;

  hipFuncSetAttribute((const void*)k_neumann, hipFuncAttributeMaxDynamicSharedMemorySize, 2*DD*RS*4);
  hipFuncSetAttribute((const void*)k_logBall, hipFuncAttributeMaxDynamicSharedMemorySize, 2*DD*KK*4);

  k_elog<<<64, 64, 0, stream>>>(phi, ElogA, P, PT);
  k_neumann<<<64, 256, 2*DD*RS*4, stream>>>(Psi, niwmu, nu, ELamT, EdiagT, cvecT, rK, Lhalf);
  hipMemsetAsync(q1, 0, (size_t)T_LEN*KK*sizeof(float), stream);
  k_q1<<<2048, 256, 0, stream>>>(mu, ELamT, q1);
  k_logBall<<<128, 256, 2*DD*KK*4, stream>>>(q1, mu, dvar, cvecT, EdiagT, rK, Lhalf, logB, mrowp, btil);
  k_pass1<<<512, 128, 0, stream>>>(P, btil, G8);
  k_chain<<<128, 256, 0, stream>>>(G8, H64, LH64, 8);
  k_chain<<<64, 256, 0, stream>>>(H64, H128, LH128, 2);
  k_pass2<<<2, 64, 0, stream>>>(LH128, logB, lpi, aB, bB);
  k_pass3<<<256, 64, 0, stream>>>(P, PT, LH64, logB, mrowp, btil, lpi, aB, bB, ah, bh, llp);
  k_out_rhat<<<2048, 256, 0, stream>>>(ah, bh, out);
  k_out_xi<<<T_LEN-1, 256, 0, stream>>>(ah, bh, ElogA, logB, out + (size_t)T_LEN*KK);
  k_ll<<<1, 128, 0, stream>>>(llp, out + (size_t)T_LEN*KK + (size_t)(T_LEN-1)*KK*KK);
}

// Round 2
// 770.402 us; speedup vs baseline: 2.0496x; 2.0496x over previous
//
#include <hip/hip_runtime.h>
#include <math.h>

#define T_LEN 8192
#define KK 64
#define DD 128
#define RS 132
#define NTERM 3
#define MUP 132

typedef __bf16  bf16x8 __attribute__((ext_vector_type(8)));
typedef float  f32x16 __attribute__((ext_vector_type(16)));

__device__ __forceinline__ float wred_max(float v){
#pragma unroll
  for (int m = 1; m < 64; m <<= 1) v = fmaxf(v, __shfl_xor(v, m, 64));
  return v;
}
__device__ __forceinline__ float wred_sum(float v){
#pragma unroll
  for (int m = 1; m < 64; m <<= 1) v += __shfl_xor(v, m, 64);
  return v;
}
__device__ __forceinline__ float digamma_f(float x){
  float r = 0.f;
  while (x < 6.f){ r -= 1.f/x; x += 1.f; }
  float ix = 1.f/x, ix2 = ix*ix;
  return r + logf(x) - 0.5f*ix - ix2*(0.0833333333f - ix2*(0.0083333333f - ix2*0.0039682540f));
}

// ---------------- ElogA, P, PT ----------------
__global__ void k_elog(const float* __restrict__ phi, float* __restrict__ ElogA,
                       float* __restrict__ P, float* __restrict__ PT){
  int i = blockIdx.x, j = threadIdx.x;
  float ph = phi[i*KK + j];
  float s  = wred_sum(ph);
  float e  = digamma_f(ph) - digamma_f(s);
  ElogA[i*KK + j] = e;
  float p = expf(e);
  P [i*KK + j] = p;
  PT[j*KK + i] = p;
}

// ---------------- Neumann inverse + logdet; emits bf16 residual Etil panels ----------------
// Ebf layout: panel p = r>>4 (r = d*128+e), Ebf[p*1024 + k*16 + (r&15)]
__global__ void __launch_bounds__(256) k_neumann(
    const float* __restrict__ Psi, const float* __restrict__ niw_mu,
    const float* __restrict__ nu_,
    __bf16* __restrict__ Ebf, float* __restrict__ EdiagT,
    float* __restrict__ cvecT, float* __restrict__ rK, float* __restrict__ Lhalf,
    float* __restrict__ sclK)
{
  extern __shared__ float lds[];
  float* Rl = lds;            // [DD][RS]
  float* Pb = lds + DD*RS;    // [DD][RS]
  __shared__ float red[256];
  __shared__ float msh[DD];
  int k = blockIdx.x, tid = threadIdx.x;
  const float* A = Psi + (size_t)k*DD*DD;

  float tl = 0.f;
  for (int d = tid; d < DD; d += 256) tl += A[d*DD + d];
  red[tid] = tl; __syncthreads();
  for (int off = 128; off > 0; off >>= 1){ if (tid < off) red[tid] += red[tid+off]; __syncthreads(); }
  float c = red[0] / (float)DD;
  __syncthreads();

  float trpow = 0.f;
  for (int idx = tid; idx < DD*DD; idx += 256){
    int d = idx >> 7, e = idx & 127;
    float v = ((d == e) ? 1.f : 0.f) - A[idx]/c;
    Rl[d*RS + e] = v; Pb[d*RS + e] = v;
    if (d == e) trpow += v;
  }
  __syncthreads();

  int tr = tid >> 4, tc = tid & 15;
  int r0 = tr*8, c0 = tc*8;
  float S[8][8];
#pragma unroll
  for (int i = 0; i < 8; i++)
#pragma unroll
    for (int j = 0; j < 8; j++){
      float v = Rl[(r0+i)*RS + c0+j];
      if (r0+i == c0+j) v += 1.f;
      S[i][j] = v;
    }

  for (int n = 2; n <= NTERM; n++){
    float Cc[8][8];
#pragma unroll
    for (int i = 0; i < 8; i++)
#pragma unroll
      for (int j = 0; j < 8; j++) Cc[i][j] = 0.f;
    for (int l = 0; l < DD; l += 4){
      float af[4][8], bf[4][8];
#pragma unroll
      for (int q = 0; q < 4; q++){
        float4 x0 = *(const float4*)&Rl[(l+q)*RS + r0];
        float4 x1 = *(const float4*)&Rl[(l+q)*RS + r0 + 4];
        af[q][0]=x0.x; af[q][1]=x0.y; af[q][2]=x0.z; af[q][3]=x0.w;
        af[q][4]=x1.x; af[q][5]=x1.y; af[q][6]=x1.z; af[q][7]=x1.w;
        float4 y0 = *(const float4*)&Pb[(l+q)*RS + c0];
        float4 y1 = *(const float4*)&Pb[(l+q)*RS + c0 + 4];
        bf[q][0]=y0.x; bf[q][1]=y0.y; bf[q][2]=y0.z; bf[q][3]=y0.w;
        bf[q][4]=y1.x; bf[q][5]=y1.y; bf[q][6]=y1.z; bf[q][7]=y1.w;
      }
#pragma unroll
      for (int q = 0; q < 4; q++)
#pragma unroll
        for (int i = 0; i < 8; i++)
#pragma unroll
          for (int j = 0; j < 8; j++)
            Cc[i][j] = fmaf(af[q][i], bf[q][j], Cc[i][j]);
    }
    __syncthreads();
#pragma unroll
    for (int i = 0; i < 8; i++){
      float4 w0, w1;
      w0.x=Cc[i][0]; w0.y=Cc[i][1]; w0.z=Cc[i][2]; w0.w=Cc[i][3];
      w1.x=Cc[i][4]; w1.y=Cc[i][5]; w1.z=Cc[i][6]; w1.w=Cc[i][7];
      *(float4*)&Pb[(r0+i)*RS + c0]     = w0;
      *(float4*)&Pb[(r0+i)*RS + c0 + 4] = w1;
    }
    __syncthreads();
    float fn = 1.f/(float)n;
#pragma unroll
    for (int i = 0; i < 8; i++)
#pragma unroll
      for (int j = 0; j < 8; j++) S[i][j] += Cc[i][j];
    if (tr == tc){
#pragma unroll
      for (int i = 0; i < 8; i++) trpow += Cc[i][i]*fn;
    }
  }

  red[tid] = trpow; __syncthreads();
  for (int off = 128; off > 0; off >>= 1){ if (tid < off) red[tid] += red[tid+off]; __syncthreads(); }
  float trsum = red[0];
  __syncthreads();

  float nu = nu_[k];
  float dl = 0.f;
  for (int i = tid; i < DD; i += 256) dl += digamma_f((nu - (float)i)*0.5f);
  red[tid] = dl; __syncthreads();
  for (int off = 128; off > 0; off >>= 1){ if (tid < off) red[tid] += red[tid+off]; __syncthreads(); }
  if (tid == 0){
    float logdetPsi = (float)DD*logf(c) - trsum;
    float Elogdet = red[0] + (float)DD*0.69314718056f - logdetPsi;
    Lhalf[k] = 0.5f*Elogdet - 0.5f*(float)DD*1.83787706641f;
    sclK[k]  = nu / c;
  }
  __syncthreads();

  float scl = nu / c;
#pragma unroll
  for (int i = 0; i < 8; i++)
#pragma unroll
    for (int j = 0; j < 8; j++){
      float sv = S[i][j];
      bool dg = (r0+i == c0+j);
      if (dg) EdiagT[(r0+i)*KK + k] = scl*sv;
      float et = scl*(sv - (dg ? 1.f : 0.f));
      int r = (r0+i)*DD + (c0+j);
      Ebf[(size_t)(r>>4)*1024 + k*16 + (r&15)] = (__bf16)et;
    }
#pragma unroll
  for (int i = 0; i < 8; i++){
    float4 w0, w1;
    w0.x=S[i][0]; w0.y=S[i][1]; w0.z=S[i][2]; w0.w=S[i][3];
    w1.x=S[i][4]; w1.y=S[i][5]; w1.z=S[i][6]; w1.w=S[i][7];
    *(float4*)&Pb[(r0+i)*RS + c0]     = w0;
    *(float4*)&Pb[(r0+i)*RS + c0 + 4] = w1;
  }
  for (int d = tid; d < DD; d += 256) msh[d] = niw_mu[k*DD + d];
  __syncthreads();
  float cv = 0.f;
  if (tid < DD){
    float acc = 0.f;
    for (int e = 0; e < DD; e++) acc += Pb[tid*RS + e]*msh[e];
    cv = scl*acc;
    cvecT[tid*KK + k] = cv;
  }
  red[tid] = (tid < DD) ? msh[tid]*cv : 0.f; __syncthreads();
  for (int off = 128; off > 0; off >>= 1){ if (tid < off) red[tid] += red[tid+off]; __syncthreads(); }
  if (tid == 0) rK[k] = red[0];
}

// ---------------- residual quad GEMM: part[rs][t][k] = sum_{r in slice} X[t,r]*Etil[r,k] ----------------
__global__ void __launch_bounds__(256) k_q1(const float* __restrict__ mu,
      const __bf16* __restrict__ Ebf, float* __restrict__ part)
{
  __shared__ float muL[64*MUP];
  __shared__ __bf16 Bp[2][64*24];
  int b = blockIdx.x;
  int rs = b & 3, tseg = b >> 2;
  int t0 = tseg*64, d0 = rs*32;
  int tid = threadIdx.x;
  int w = tid >> 6, lane = tid & 63;
  int tl = (w>>1)*32 + (lane&31);
  int nc = (w&1)*32 + (lane&31);
  int k0 = (lane>>5)*8;

  for (int v = tid; v < 64*32; v += 256){
    int t = v >> 5, seg = v & 31;
    float4 x = *(const float4*)&mu[(size_t)(t0+t)*DD + seg*4];
    *(float4*)&muL[t*MUP + seg*4] = x;
  }
  {
    const unsigned long long* gp = (const unsigned long long*)(Ebf + (size_t)(d0*8)*1024);
    unsigned long long v = gp[tid];
    *((unsigned long long*)&Bp[0][(tid>>2)*24 + (tid&3)*4]) = v;
  }
  __syncthreads();

  f32x16 acc;
#pragma unroll
  for (int i = 0; i < 16; i++) acc[i] = 0.f;

  for (int s = 0; s < 256; s++){
    unsigned long long pre = 0ull;
    if (s < 255){
      const unsigned long long* gp = (const unsigned long long*)(Ebf + (size_t)(d0*8 + s + 1)*1024);
      pre = gp[tid];
    }
    int d = d0 + (s>>3), e0 = (s&7)<<4;
    float mud = muL[tl*MUP + d];
    float4 m0 = *(const float4*)&muL[tl*MUP + e0 + k0];
    float4 m1 = *(const float4*)&muL[tl*MUP + e0 + k0 + 4];
    bf16x8 af;
    af[0] = (__bf16)(mud*m0.x); af[1] = (__bf16)(mud*m0.y);
    af[2] = (__bf16)(mud*m0.z); af[3] = (__bf16)(mud*m0.w);
    af[4] = (__bf16)(mud*m1.x); af[5] = (__bf16)(mud*m1.y);
    af[6] = (__bf16)(mud*m1.z); af[7] = (__bf16)(mud*m1.w);
    bf16x8 bfr = *(const bf16x8*)&Bp[s&1][nc*24 + k0];
    acc = __builtin_amdgcn_mfma_f32_32x32x16_bf16(af, bfr, acc, 0, 0, 0);
    if (s < 255){
      *((unsigned long long*)&Bp[(s+1)&1][(tid>>2)*24 + (tid&3)*4]) = pre;
    }
    __syncthreads();
  }

  float* dst = part + (size_t)rs*T_LEN*KK;
#pragma unroll
  for (int r = 0; r < 16; r++){
    int row = (r&3) + 8*(r>>2) + 4*(lane>>5);
    int t = t0 + (w>>1)*32 + row;
    dst[(size_t)t*KK + nc] = acc[r];
  }
}

// ---------------- finalize logB, rowmax m_t, btil ----------------
__global__ void __launch_bounds__(256) k_logBall(
    const float* __restrict__ part, const float* __restrict__ mu, const float* __restrict__ dvar,
    const float* __restrict__ cvecT, const float* __restrict__ EdiagT,
    const float* __restrict__ rK, const float* __restrict__ Lhalf, const float* __restrict__ sclK,
    float* __restrict__ logB, float* __restrict__ mrow, float* __restrict__ btil)
{
  extern __shared__ float lds[];
  float* cv = lds; float* ed = lds + DD*KK;
  int tid = threadIdx.x; int k = tid & 63; int w = tid >> 6;
  for (int v = tid; v < DD*KK; v += 256){ cv[v] = cvecT[v]; ed[v] = EdiagT[v]; }
  __syncthreads();
  float rk = rK[k], lh = Lhalf[k], scl = sclK[k];
  int tbase = blockIdx.x*64 + w*16;
  for (int ii = 0; ii < 16; ii++){
    int t = tbase + ii;
    const float* murow = mu   + (size_t)t*DD;
    const float* dvrow = dvar + (size_t)t*DD;
    float a1 = 0.f, a2 = 0.f, ss = 0.f;
    for (int d = 0; d < DD; d++){
      float md = murow[d];
      float vd = fmaxf(dvrow[d], 0.f);
      a1 = fmaf(md, cv[d*KK + k], a1);
      a2 = fmaf(vd, ed[d*KK + k], a2);
      ss = fmaf(md, md, ss);
    }
    float q = scl*ss
            + part[(size_t)0*T_LEN*KK + (size_t)t*KK + k]
            + part[(size_t)1*T_LEN*KK + (size_t)t*KK + k]
            + part[(size_t)2*T_LEN*KK + (size_t)t*KK + k]
            + part[(size_t)3*T_LEN*KK + (size_t)t*KK + k];
    float lb = lh - 0.5f*(q - 2.f*a1 + rk + a2);
    float m  = wred_max(lb);
    logB[(size_t)t*KK + k] = lb;
    btil[(size_t)t*KK + k] = expf(lb - m);
    if (k == 0) mrow[t] = m;
  }
}

// ---------------- pass1: 8-step chunk operators G8 (one wave per chunk) ----------------
#define GROW(r) ((r)*68 + ((((r)>>3)&3)*4))
__global__ void __launch_bounds__(128) k_pass1(const float* __restrict__ Pm,
     const float* __restrict__ btil, float* __restrict__ G8)
{
  __shared__ float lds_s[4352 + 2*4368];
  float* Pl = lds_s;
  int tid = threadIdx.x;
  int w = tid >> 6, lane = tid & 63;
  float* G = lds_s + 4352 + w*4368;
  for (int v = tid; v < 4096; v += 128) Pl[(v>>6)*68 + (v&63)] = Pm[v];
  int chunk = blockIdx.x*2 + w;
  int ti = lane >> 3, tj = lane & 7;
  int r0 = ti*8, c0 = tj*8;
  for (int v = lane; v < 4096; v += 64){
    int i = v >> 6, j = v & 63;
    G[GROW(i) + j] = (i == j) ? 1.f : 0.f;
  }
  __syncthreads();

  for (int s = 0; s < 8; s++){
    int t = chunk*8 + s;
    if (t < 1) continue;
    float acc[8][8];
#pragma unroll
    for (int i = 0; i < 8; i++)
#pragma unroll
      for (int j = 0; j < 8; j++) acc[i][j] = 0.f;
    for (int l = 0; l < 64; l += 4){
      float af[8][4];
#pragma unroll
      for (int i = 0; i < 8; i++){
        float4 x = *(const float4*)&G[GROW(r0+i) + l];
        af[i][0]=x.x; af[i][1]=x.y; af[i][2]=x.z; af[i][3]=x.w;
      }
      float bf[4][8];
#pragma unroll
      for (int q = 0; q < 4; q++){
        float4 y0 = *(const float4*)&Pl[(l+q)*68 + c0];
        float4 y1 = *(const float4*)&Pl[(l+q)*68 + c0 + 4];
        bf[q][0]=y0.x; bf[q][1]=y0.y; bf[q][2]=y0.z; bf[q][3]=y0.w;
        bf[q][4]=y1.x; bf[q][5]=y1.y; bf[q][6]=y1.z; bf[q][7]=y1.w;
      }
#pragma unroll
      for (int q = 0; q < 4; q++)
#pragma unroll
        for (int i = 0; i < 8; i++)
#pragma unroll
          for (int j = 0; j < 8; j++)
            acc[i][j] = fmaf(af[i][q], bf[q][j], acc[i][j]);
    }
    float4 bb0 = *(const float4*)&btil[(size_t)t*KK + c0];
    float4 bb1 = *(const float4*)&btil[(size_t)t*KK + c0 + 4];
    float bj[8] = {bb0.x,bb0.y,bb0.z,bb0.w,bb1.x,bb1.y,bb1.z,bb1.w};
    float mx = 0.f;
#pragma unroll
    for (int i = 0; i < 8; i++)
#pragma unroll
      for (int j = 0; j < 8; j++){ acc[i][j] *= bj[j]; mx = fmaxf(mx, acc[i][j]); }
    mx = wred_max(mx);
    float inv = 1.f/mx;
#pragma unroll
    for (int i = 0; i < 8; i++){
      float4 w0, w1;
      w0.x=acc[i][0]*inv; w0.y=acc[i][1]*inv; w0.z=acc[i][2]*inv; w0.w=acc[i][3]*inv;
      w1.x=acc[i][4]*inv; w1.y=acc[i][5]*inv; w1.z=acc[i][6]*inv; w1.w=acc[i][7]*inv;
      *(float4*)&G[GROW(r0+i) + c0]     = w0;
      *(float4*)&G[GROW(r0+i) + c0 + 4] = w1;
    }
  }
  float* dst = G8 + (size_t)chunk*4096;
  for (int v = lane; v < 4096; v += 64) dst[v] = G[GROW(v>>6) + (v&63)];
}

// ---------------- chain-combine ----------------
__global__ void __launch_bounds__(256) k_chain(const float* __restrict__ src,
        float* __restrict__ dstLin, float* __restrict__ dstLog, int chain)
{
  __shared__ float X[64*68];
  __shared__ float Y[64*68];
  __shared__ float red[256];
  int cb = blockIdx.x, tid = threadIdx.x;
  const float* s0 = src + (size_t)cb*chain*4096;
  for (int v = tid; v < 4096; v += 256) X[(v>>6)*68 + (v&63)] = s0[v];
  int ti = tid >> 4, tj = tid & 15;
  int r0 = ti*4, c0 = tj*4;
  for (int j = 1; j < chain; j++){
    const float* sj = s0 + (size_t)j*4096;
    for (int v = tid; v < 4096; v += 256) Y[(v>>6)*68 + (v&63)] = sj[v];
    __syncthreads();
    float acc[4][4];
#pragma unroll
    for (int i = 0; i < 4; i++)
#pragma unroll
      for (int q = 0; q < 4; q++) acc[i][q] = 0.f;
    for (int l = 0; l < 64; l++){
      float a0 = X[(r0+0)*68 + l], a1 = X[(r0+1)*68 + l];
      float a2 = X[(r0+2)*68 + l], a3 = X[(r0+3)*68 + l];
      float4 yy = *(const float4*)&Y[l*68 + c0];
      acc[0][0]=fmaf(a0,yy.x,acc[0][0]); acc[0][1]=fmaf(a0,yy.y,acc[0][1]); acc[0][2]=fmaf(a0,yy.z,acc[0][2]); acc[0][3]=fmaf(a0,yy.w,acc[0][3]);
      acc[1][0]=fmaf(a1,yy.x,acc[1][0]); acc[1][1]=fmaf(a1,yy.y,acc[1][1]); acc[1][2]=fmaf(a1,yy.z,acc[1][2]); acc[1][3]=fmaf(a1,yy.w,acc[1][3]);
      acc[2][0]=fmaf(a2,yy.x,acc[2][0]); acc[2][1]=fmaf(a2,yy.y,acc[2][1]); acc[2][2]=fmaf(a2,yy.z,acc[2][2]); acc[2][3]=fmaf(a2,yy.w,acc[2][3]);
      acc[3][0]=fmaf(a3,yy.x,acc[3][0]); acc[3][1]=fmaf(a3,yy.y,acc[3][1]); acc[3][2]=fmaf(a3,yy.z,acc[3][2]); acc[3][3]=fmaf(a3,yy.w,acc[3][3]);
    }
    float mx = 0.f;
#pragma unroll
    for (int i = 0; i < 4; i++)
#pragma unroll
      for (int q = 0; q < 4; q++) mx = fmaxf(mx, acc[i][q]);
    red[tid] = mx; __syncthreads();
    for (int off = 128; off > 0; off >>= 1){ if (tid < off) red[tid] = fmaxf(red[tid], red[tid+off]); __syncthreads(); }
    float inv = 1.f/red[0];
    __syncthreads();
#pragma unroll
    for (int i = 0; i < 4; i++){
      float4 wv; wv.x=acc[i][0]*inv; wv.y=acc[i][1]*inv; wv.z=acc[i][2]*inv; wv.w=acc[i][3]*inv;
      *(float4*)&X[(r0+i)*68 + c0] = wv;
    }
    __syncthreads();
  }
  for (int v = tid; v < 4096; v += 256){
    float vv = X[(v>>6)*68 + (v&63)];
    dstLin[(size_t)cb*4096 + v] = vv;
    dstLog[(size_t)cb*4096 + v] = logf(vv);
  }
}

// ---------------- pass2: sequential scan over 64 linear 128-step operators ----------------
__global__ void __launch_bounds__(256) k_pass2(const float* __restrict__ H128,
    const float* __restrict__ logB, const float* __restrict__ log_pi,
    float* __restrict__ aB, float* __restrict__ bB)
{
  __shared__ float Hb[2][64*68];
  __shared__ float sv[64];
  __shared__ float partl[4][64];
  int tid = threadIdx.x;
  int w = tid >> 6, lane = tid & 63;
  bool fwd = (blockIdx.x == 0);
  int nsteps = fwd ? 64 : 63;

  if (w == 0){
    if (fwd){
      float v = log_pi[lane] + logB[lane];
      float m = wred_max(v);
      float e = expf(v - m);
      float s = wred_sum(e);
      sv[lane] = e/s;
    } else {
      sv[lane] = 1.f;
      bB[63*64 + lane] = 1.f;
    }
  }

  int c0i = fwd ? 0 : 63;
  float4 r0, r1, r2, r3;
  {
    const float4* g = (const float4*)(H128 + (size_t)c0i*4096 + tid*16);
    r0 = g[0]; r1 = g[1]; r2 = g[2]; r3 = g[3];
  }
  for (int it = 0; it < nsteps; it++){
    int c = fwd ? it : 63 - it;
    int buf = it & 1;
    if (fwd){
      int i = tid >> 2, cc = (tid & 3)*16;
      *(float4*)&Hb[buf][i*68 + cc + 0]  = r0;
      *(float4*)&Hb[buf][i*68 + cc + 4]  = r1;
      *(float4*)&Hb[buf][i*68 + cc + 8]  = r2;
      *(float4*)&Hb[buf][i*68 + cc + 12] = r3;
    } else {
      // transposed store: Hb[j][i] = H[i][j]
      int i = tid >> 2, cc = (tid & 3)*16;
      float vals[16] = {r0.x,r0.y,r0.z,r0.w, r1.x,r1.y,r1.z,r1.w,
                        r2.x,r2.y,r2.z,r2.w, r3.x,r3.y,r3.z,r3.w};
#pragma unroll
      for (int q = 0; q < 16; q++) Hb[buf][(cc+q)*68 + i] = vals[q];
    }
    if (it + 1 < nsteps){
      int cn = fwd ? it + 1 : 63 - (it + 1);
      const float4* g = (const float4*)(H128 + (size_t)cn*4096 + tid*16);
      r0 = g[0]; r1 = g[1]; r2 = g[2]; r3 = g[3];
    }
    __syncthreads();
    // partial matvec over quarter w
    float p = 0.f;
#pragma unroll
    for (int q = 0; q < 16; q++){
      int i = w*16 + q;
      p = fmaf(sv[i], Hb[buf][i*68 + lane], p);
    }
    partl[w][lane] = p;
    __syncthreads();
    if (w == 0){
      float v = partl[0][lane] + partl[1][lane] + partl[2][lane] + partl[3][lane];
      if (fwd){
        float s = wred_sum(v);
        float a = v/s;
        sv[lane] = a;
        aB[c*64 + lane] = a;
      } else {
        float m = wred_max(v);
        float bb = v/m;
        sv[lane] = bb;
        bB[(c-1)*64 + lane] = bb;
      }
    }
  }
}

// ---------------- pass3: per-64-step-chunk exact recurrences ----------------
__global__ void k_pass3(const float* __restrict__ Pm, const float* __restrict__ PTm,
   const float* __restrict__ LH64,
   const float* __restrict__ logB, const float* __restrict__ mrow, const float* __restrict__ btil,
   const float* __restrict__ log_pi,
   const float* __restrict__ aB, const float* __restrict__ bB,
   float* __restrict__ alphahat, float* __restrict__ betahat, float* __restrict__ llpart)
{
  __shared__ float Hl[64*68];
  __shared__ float vl[64];
  int lane = threadIdx.x;
  int bid = blockIdx.x;
  if (bid < 128){
    int c = bid;
    float Preg[64];
#pragma unroll
    for (int i = 0; i < 64; i++) Preg[i] = Pm[i*64 + lane];
    float a; float llacc = 0.f;
    int tstart;
    if (c == 0){
      float v = log_pi[lane] + logB[lane];
      float m = wred_max(v);
      float e = expf(v - m);
      float s = wred_sum(e);
      a = e/s;
      llacc = m + logf(s);
      alphahat[lane] = a;
      tstart = 1;
    } else if (c & 1){
      float lp;
      if (c == 1){
        float v = log_pi[lane] + logB[lane];
        float m = wred_max(v);
        lp = v - m;
      } else {
        lp = logf(aB[((c-1)/2 - 1)*64 + lane]);
      }
      for (int u = lane; u < 1024; u += 64){
        float4 x = ((const float4*)(LH64 + (size_t)(c-1)*4096))[u];
        int row = u >> 4, col = (u & 15)*4;
        *(float4*)&Hl[row*68 + col] = x;
      }
      vl[lane] = lp;
      __syncthreads();
      float mx = -3.0e38f;
      for (int i = 0; i < 64; i++) mx = fmaxf(mx, vl[i] + Hl[i*68 + lane]);
      float s = 0.f;
      for (int i = 0; i < 64; i++) s += expf(vl[i] + Hl[i*68 + lane] - mx);
      float ln = mx + logf(s);
      float mm = wred_max(ln);
      float e  = expf(ln - mm);
      float ss = wred_sum(e);
      a = e/ss;
      __syncthreads();
      tstart = c*64;
    } else {
      a = aB[(c/2 - 1)*64 + lane];
      tstart = c*64;
    }
    int tend = c*64 + 64;
    for (int t = tstart; t < tend; t++){
      float pred = 0.f;
#pragma unroll
      for (int i = 0; i < 64; i++) pred = fmaf(__shfl(a, i, 64), Preg[i], pred);
      float at = pred * btil[(size_t)t*KK + lane];
      float s  = wred_sum(at);
      a = at / s;
      llacc += logf(s) + mrow[t];
      alphahat[(size_t)t*KK + lane] = a;
    }
    if (lane == 0) llpart[c] = llacc;
  } else {
    int c = bid - 128;
    float PTreg[64];
#pragma unroll
    for (int j = 0; j < 64; j++) PTreg[j] = PTm[j*64 + lane];
    float b, lb;
    if (c == 127){
      b = 1.f; lb = 0.f;
    } else if (c & 1){
      b = bB[((c-1)/2)*64 + lane];
      lb = logf(b);
    } else {
      float lbin = logf(bB[(c/2)*64 + lane]);
      for (int u = lane; u < 1024; u += 64){
        float4 x = ((const float4*)(LH64 + (size_t)(c+1)*4096))[u];
        int row = u >> 4, col = (u & 15)*4;
        Hl[(col+0)*68 + row] = x.x; Hl[(col+1)*68 + row] = x.y;
        Hl[(col+2)*68 + row] = x.z; Hl[(col+3)*68 + row] = x.w;
      }
      vl[lane] = lbin;
      __syncthreads();
      float mx = -3.0e38f;
      for (int j = 0; j < 64; j++) mx = fmaxf(mx, Hl[j*68 + lane] + vl[j]);
      float s = 0.f;
      for (int j = 0; j < 64; j++) s += expf(Hl[j*68 + lane] + vl[j] - mx);
      float ln = mx + logf(s);
      float mm = wred_max(ln);
      lb = ln - mm;
      b = expf(lb);
      __syncthreads();
    }
    int t1 = c*64 + 63;
    betahat[(size_t)t1*KK + lane] = b;
    for (int t = t1 - 1; t >= c*64; t--){
      float lv = (logB[(size_t)(t+1)*KK + lane] - mrow[t+1]) + lb;
      float vm = wred_max(lv);
      float vv = expf(lv - vm);
      float bn = 0.f;
#pragma unroll
      for (int j = 0; j < 64; j++) bn = fmaf(PTreg[j], __shfl(vv, j, 64), bn);
      float bmax = wred_max(bn);
      b = bn / bmax;
      lb = logf(b);
      betahat[(size_t)t*KK + lane] = b;
    }
  }
}

// ---------------- outputs ----------------
__global__ void k_out_rhat(const float* __restrict__ ah, const float* __restrict__ bh,
                           float* __restrict__ out){
  int tid = threadIdx.x; int w = tid >> 6, lane = tid & 63;
  int t = blockIdx.x*4 + w;
  float la = logf(ah[(size_t)t*KK + lane]);
  float lb = logf(bh[(size_t)t*KK + lane]);
  float s = la + lb;
  float m = wred_max(s);
  float p = (m < -3.0e37f) ? 1.f : expf(s - m);
  float ss = wred_sum(p);
  out[(size_t)t*KK + lane] = p/ss;
}

__global__ void __launch_bounds__(256) k_out_xi(const float* __restrict__ ah,
     const float* __restrict__ bh, const float* __restrict__ ElogA,
     const float* __restrict__ logB, float* __restrict__ out)
{
  __shared__ float la[64], wc[64];
  __shared__ float red[256];
  int tid = threadIdx.x;
  int t = blockIdx.x + 1;
  if (tid < 64) la[tid] = logf(ah[(size_t)(t-1)*KK + tid]);
  else if (tid < 128){
    int j = tid - 64;
    wc[j] = logB[(size_t)t*KK + j] + logf(bh[(size_t)t*KK + j]);
  }
  __syncthreads();
  int r = tid >> 6, j = tid & 63;
  float sv[16];
  float mx = -3.0e38f;
#pragma unroll
  for (int n = 0; n < 16; n++){
    int i = r + n*4;
    float s = la[i] + ElogA[i*KK + j] + wc[j];
    sv[n] = s;
    mx = fmaxf(mx, s);
  }
  red[tid] = mx; __syncthreads();
  for (int off = 128; off > 0; off >>= 1){ if (tid < off) red[tid] = fmaxf(red[tid], red[tid+off]); __syncthreads(); }
  float m = red[0];
  __syncthreads();
  bool degen = !(m > -3.0e37f);
  float pv[16]; float ps = 0.f;
#pragma unroll
  for (int n = 0; n < 16; n++){
    float p = degen ? 1.f : expf(sv[n] - m);
    pv[n] = p; ps += p;
  }
  red[tid] = ps; __syncthreads();
  for (int off = 128; off > 0; off >>= 1){ if (tid < off) red[tid] += red[tid+off]; __syncthreads(); }
  float inv = 1.f/red[0];
  float* dst = out + (size_t)(t-1)*4096;
#pragma unroll
  for (int n = 0; n < 16; n++){
    int i = r + n*4;
    dst[i*KK + j] = pv[n]*inv;
  }
}

__global__ void k_ll(const float* __restrict__ llpart, float* __restrict__ out){
  __shared__ float red[128];
  int tid = threadIdx.x;
  red[tid] = llpart[tid];
  __syncthreads();
  for (int off = 64; off > 0; off >>= 1){ if (tid < off) red[tid] += red[tid+off]; __syncthreads(); }
  if (tid == 0) out[0] = red[0];
}

extern "C" void kernel_launch(void* const* d_in, const int* in_sizes, int n_in,
                              void* d_out, int out_size, void* d_ws, size_t ws_size,
                              hipStream_t stream)
{
  const float* mu    = (const float*)d_in[0];
  const float* dvar  = (const float*)d_in[1];
  const float* niwmu = (const float*)d_in[2];
  const float* Psi   = (const float*)d_in[3];
  const float* nu    = (const float*)d_in[4];
  const float* phi   = (const float*)d_in[5];
  const float* lpi   = (const float*)d_in[6];
  float* out = (float*)d_out;
  float* ws  = (float*)d_ws;

  size_t o = 0;
  float* EbfF   = ws + o; o += (size_t)DD*DD*KK/2;   // bf16 region (1M bf16 = 512K floats)
  float* EdiagT = ws + o; o += (size_t)DD*KK;
  float* cvecT  = ws + o; o += (size_t)DD*KK;
  float* rK     = ws + o; o += KK;
  float* Lhalf  = ws + o; o += KK;
  float* sclK   = ws + o; o += KK;
  float* ElogA  = ws + o; o += KK*KK;
  float* P      = ws + o; o += KK*KK;
  float* PT     = ws + o; o += KK*KK;
  float* logB   = ws + o; o += (size_t)T_LEN*KK;
  float* mrowp  = ws + o; o += T_LEN;
  float* btil   = ws + o; o += (size_t)T_LEN*KK;
  float* G8     = ws + o; o += (size_t)1024*4096;    // also aliases `part` (4*T*K) pre-pass1
  float* H64    = ws + o; o += (size_t)128*4096;
  float* LH64   = ws + o; o += (size_t)128*4096;
  float* H128   = ws + o; o += (size_t)64*4096;
  float* LH128  = ws + o; o += (size_t)64*4096;
  float* aB     = ws + o; o += 64*64;
  float* bB     = ws + o; o += 64*64;
  float* llp    = ws + o; o += 128;
  float* ah     = ws + o; o += (size_t)T_LEN*KK;
  float* bh     = ws + o; o += (size_t)T_LEN*KK;
  if (ws_size < o*sizeof(float)) return;

  __bf16* Ebf = (__bf16*)EbfF;
  float*  part = G8;   // alias: part consumed by k_logBall before k_pass1 writes G8

  hipFuncSetAttribute((const void*)k_neumann, hipFuncAttributeMaxDynamicSharedMemorySize, 2*DD*RS*4);
  hipFuncSetAttribute((const void*)k_logBall, hipFuncAttributeMaxDynamicSharedMemorySize, 2*DD*KK*4);

  k_elog<<<64, 64, 0, stream>>>(phi, ElogA, P, PT);
  k_neumann<<<64, 256, 2*DD*RS*4, stream>>>(Psi, niwmu, nu, Ebf, EdiagT, cvecT, rK, Lhalf, sclK);
  k_q1<<<512, 256, 0, stream>>>(mu, Ebf, part);
  k_logBall<<<128, 256, 2*DD*KK*4, stream>>>(part, mu, dvar, cvecT, EdiagT, rK, Lhalf, sclK, logB, mrowp, btil);
  k_pass1<<<512, 128, 0, stream>>>(P, btil, G8);
  k_chain<<<128, 256, 0, stream>>>(G8, H64, LH64, 8);
  k_chain<<<64, 256, 0, stream>>>(H64, H128, LH128, 2);
  k_pass2<<<2, 256, 0, stream>>>(H128, logB, lpi, aB, bB);
  k_pass3<<<256, 64, 0, stream>>>(P, PT, LH64, logB, mrowp, btil, lpi, aB, bB, ah, bh, llp);
  k_out_rhat<<<2048, 256, 0, stream>>>(ah, bh, out);
  k_out_xi<<<T_LEN-1, 256, 0, stream>>>(ah, bh, ElogA, logB, out + (size_t)T_LEN*KK);
  k_ll<<<1, 128, 0, stream>>>(llp, out + (size_t)T_LEN*KK + (size_t)(T_LEN-1)*KK*KK);
}

// Round 3
// 626.177 us; speedup vs baseline: 2.5216x; 1.2303x over previous
//
#include <hip/hip_runtime.h>
#include <math.h>

#define T_LEN 8192
#define KK 64
#define DD 128
#define RS 132
#define NTERM 3
#define MUP 132

typedef __bf16  bf16x8 __attribute__((ext_vector_type(8)));
typedef float  f32x16 __attribute__((ext_vector_type(16)));

__device__ __forceinline__ float wred_max(float v){
#pragma unroll
  for (int m = 1; m < 64; m <<= 1) v = fmaxf(v, __shfl_xor(v, m, 64));
  return v;
}
__device__ __forceinline__ float wred_sum(float v){
#pragma unroll
  for (int m = 1; m < 64; m <<= 1) v += __shfl_xor(v, m, 64);
  return v;
}
__device__ __forceinline__ float digamma_f(float x){
  float r = 0.f;
  while (x < 6.f){ r -= 1.f/x; x += 1.f; }
  float ix = 1.f/x, ix2 = ix*ix;
  return r + logf(x) - 0.5f*ix - ix2*(0.0833333333f - ix2*(0.0083333333f - ix2*0.0039682540f));
}

// ---------------- ElogA, P, PT ----------------
__global__ void k_elog(const float* __restrict__ phi, float* __restrict__ ElogA,
                       float* __restrict__ P, float* __restrict__ PT){
  int i = blockIdx.x, j = threadIdx.x;
  float ph = phi[i*KK + j];
  float s  = wred_sum(ph);
  float e  = digamma_f(ph) - digamma_f(s);
  ElogA[i*KK + j] = e;
  float p = expf(e);
  P [i*KK + j] = p;
  PT[j*KK + i] = p;
}

// ---------------- Neumann inverse + logdet; emits bf16 residual Etil panels ----------------
__global__ void __launch_bounds__(256, 1) k_neumann(
    const float* __restrict__ Psi, const float* __restrict__ niw_mu,
    const float* __restrict__ nu_,
    __bf16* __restrict__ Ebf, float* __restrict__ EdiagT,
    float* __restrict__ cvecT, float* __restrict__ rK, float* __restrict__ Lhalf,
    float* __restrict__ sclK)
{
  extern __shared__ float lds[];
  float* Rl = lds;            // [DD][RS]
  float* Pb = lds + DD*RS;    // [DD][RS]
  __shared__ float red[256];
  __shared__ float msh[DD];
  int k = blockIdx.x, tid = threadIdx.x;
  const float* A = Psi + (size_t)k*DD*DD;

  float tl = 0.f;
  for (int d = tid; d < DD; d += 256) tl += A[d*DD + d];
  red[tid] = tl; __syncthreads();
  for (int off = 128; off > 0; off >>= 1){ if (tid < off) red[tid] += red[tid+off]; __syncthreads(); }
  float c = red[0] / (float)DD;
  __syncthreads();

  float trpow = 0.f;
  for (int idx = tid; idx < DD*DD; idx += 256){
    int d = idx >> 7, e = idx & 127;
    float v = ((d == e) ? 1.f : 0.f) - A[idx]/c;
    Rl[d*RS + e] = v; Pb[d*RS + e] = v;
    if (d == e) trpow += v;
  }
  __syncthreads();

  int tr = tid >> 4, tc = tid & 15;
  int r0 = tr*8, c0 = tc*8;
  float S[8][8];
#pragma unroll
  for (int i = 0; i < 8; i++)
#pragma unroll
    for (int j = 0; j < 8; j++){
      float v = Rl[(r0+i)*RS + c0+j];
      if (r0+i == c0+j) v += 1.f;
      S[i][j] = v;
    }

  for (int n = 2; n <= NTERM; n++){
    float Cc[8][8];
#pragma unroll
    for (int i = 0; i < 8; i++)
#pragma unroll
      for (int j = 0; j < 8; j++) Cc[i][j] = 0.f;
    for (int l = 0; l < DD; l += 4){
      float af[4][8], bf[4][8];
#pragma unroll
      for (int q = 0; q < 4; q++){
        float4 x0 = *(const float4*)&Rl[(l+q)*RS + r0];
        float4 x1 = *(const float4*)&Rl[(l+q)*RS + r0 + 4];
        af[q][0]=x0.x; af[q][1]=x0.y; af[q][2]=x0.z; af[q][3]=x0.w;
        af[q][4]=x1.x; af[q][5]=x1.y; af[q][6]=x1.z; af[q][7]=x1.w;
        float4 y0 = *(const float4*)&Pb[(l+q)*RS + c0];
        float4 y1 = *(const float4*)&Pb[(l+q)*RS + c0 + 4];
        bf[q][0]=y0.x; bf[q][1]=y0.y; bf[q][2]=y0.z; bf[q][3]=y0.w;
        bf[q][4]=y1.x; bf[q][5]=y1.y; bf[q][6]=y1.z; bf[q][7]=y1.w;
      }
#pragma unroll
      for (int q = 0; q < 4; q++)
#pragma unroll
        for (int i = 0; i < 8; i++)
#pragma unroll
          for (int j = 0; j < 8; j++)
            Cc[i][j] = fmaf(af[q][i], bf[q][j], Cc[i][j]);
    }
    __syncthreads();
#pragma unroll
    for (int i = 0; i < 8; i++){
      float4 w0, w1;
      w0.x=Cc[i][0]; w0.y=Cc[i][1]; w0.z=Cc[i][2]; w0.w=Cc[i][3];
      w1.x=Cc[i][4]; w1.y=Cc[i][5]; w1.z=Cc[i][6]; w1.w=Cc[i][7];
      *(float4*)&Pb[(r0+i)*RS + c0]     = w0;
      *(float4*)&Pb[(r0+i)*RS + c0 + 4] = w1;
    }
    __syncthreads();
    float fn = 1.f/(float)n;
#pragma unroll
    for (int i = 0; i < 8; i++)
#pragma unroll
      for (int j = 0; j < 8; j++) S[i][j] += Cc[i][j];
    if (tr == tc){
#pragma unroll
      for (int i = 0; i < 8; i++) trpow += Cc[i][i]*fn;
    }
  }

  red[tid] = trpow; __syncthreads();
  for (int off = 128; off > 0; off >>= 1){ if (tid < off) red[tid] += red[tid+off]; __syncthreads(); }
  float trsum = red[0];
  __syncthreads();

  float nu = nu_[k];
  float dl = 0.f;
  for (int i = tid; i < DD; i += 256) dl += digamma_f((nu - (float)i)*0.5f);
  red[tid] = dl; __syncthreads();
  for (int off = 128; off > 0; off >>= 1){ if (tid < off) red[tid] += red[tid+off]; __syncthreads(); }
  if (tid == 0){
    float logdetPsi = (float)DD*logf(c) - trsum;
    float Elogdet = red[0] + (float)DD*0.69314718056f - logdetPsi;
    Lhalf[k] = 0.5f*Elogdet - 0.5f*(float)DD*1.83787706641f;
    sclK[k]  = nu / c;
  }
  __syncthreads();

  float scl = nu / c;
#pragma unroll
  for (int i = 0; i < 8; i++)
#pragma unroll
    for (int j = 0; j < 8; j++){
      float sv = S[i][j];
      bool dg = (r0+i == c0+j);
      if (dg) EdiagT[(r0+i)*KK + k] = scl*sv;
      float et = scl*(sv - (dg ? 1.f : 0.f));
      int r = (r0+i)*DD + (c0+j);
      Ebf[(size_t)(r>>4)*1024 + k*16 + (r&15)] = (__bf16)et;
    }
#pragma unroll
  for (int i = 0; i < 8; i++){
    float4 w0, w1;
    w0.x=S[i][0]; w0.y=S[i][1]; w0.z=S[i][2]; w0.w=S[i][3];
    w1.x=S[i][4]; w1.y=S[i][5]; w1.z=S[i][6]; w1.w=S[i][7];
    *(float4*)&Pb[(r0+i)*RS + c0]     = w0;
    *(float4*)&Pb[(r0+i)*RS + c0 + 4] = w1;
  }
  for (int d = tid; d < DD; d += 256) msh[d] = niw_mu[k*DD + d];
  __syncthreads();
  float cv = 0.f;
  if (tid < DD){
    float acc = 0.f;
    for (int e = 0; e < DD; e++) acc += Pb[tid*RS + e]*msh[e];
    cv = scl*acc;
    cvecT[tid*KK + k] = cv;
  }
  red[tid] = (tid < DD) ? msh[tid]*cv : 0.f; __syncthreads();
  for (int off = 128; off > 0; off >>= 1){ if (tid < off) red[tid] += red[tid+off]; __syncthreads(); }
  if (tid == 0) rK[k] = red[0];
}

// ---------------- residual quad GEMM ----------------
__global__ void __launch_bounds__(256) k_q1(const float* __restrict__ mu,
      const __bf16* __restrict__ Ebf, float* __restrict__ part)
{
  __shared__ float muL[64*MUP];
  __shared__ __bf16 Bp[2][64*24];
  int b = blockIdx.x;
  int rs = b & 3, tseg = b >> 2;
  int t0 = tseg*64, d0 = rs*32;
  int tid = threadIdx.x;
  int w = tid >> 6, lane = tid & 63;
  int tl = (w>>1)*32 + (lane&31);
  int nc = (w&1)*32 + (lane&31);
  int k0 = (lane>>5)*8;

  for (int v = tid; v < 64*32; v += 256){
    int t = v >> 5, seg = v & 31;
    float4 x = *(const float4*)&mu[(size_t)(t0+t)*DD + seg*4];
    *(float4*)&muL[t*MUP + seg*4] = x;
  }
  {
    const unsigned long long* gp = (const unsigned long long*)(Ebf + (size_t)(d0*8)*1024);
    unsigned long long v = gp[tid];
    *((unsigned long long*)&Bp[0][(tid>>2)*24 + (tid&3)*4]) = v;
  }
  __syncthreads();

  f32x16 acc;
#pragma unroll
  for (int i = 0; i < 16; i++) acc[i] = 0.f;

  for (int s = 0; s < 256; s++){
    unsigned long long pre = 0ull;
    if (s < 255){
      const unsigned long long* gp = (const unsigned long long*)(Ebf + (size_t)(d0*8 + s + 1)*1024);
      pre = gp[tid];
    }
    int d = d0 + (s>>3), e0 = (s&7)<<4;
    float mud = muL[tl*MUP + d];
    float4 m0 = *(const float4*)&muL[tl*MUP + e0 + k0];
    float4 m1 = *(const float4*)&muL[tl*MUP + e0 + k0 + 4];
    bf16x8 af;
    af[0] = (__bf16)(mud*m0.x); af[1] = (__bf16)(mud*m0.y);
    af[2] = (__bf16)(mud*m0.z); af[3] = (__bf16)(mud*m0.w);
    af[4] = (__bf16)(mud*m1.x); af[5] = (__bf16)(mud*m1.y);
    af[6] = (__bf16)(mud*m1.z); af[7] = (__bf16)(mud*m1.w);
    bf16x8 bfr = *(const bf16x8*)&Bp[s&1][nc*24 + k0];
    acc = __builtin_amdgcn_mfma_f32_32x32x16_bf16(af, bfr, acc, 0, 0, 0);
    if (s < 255){
      *((unsigned long long*)&Bp[(s+1)&1][(tid>>2)*24 + (tid&3)*4]) = pre;
    }
    __syncthreads();
  }

  float* dst = part + (size_t)rs*T_LEN*KK;
#pragma unroll
  for (int r = 0; r < 16; r++){
    int row = (r&3) + 8*(r>>2) + 4*(lane>>5);
    int t = t0 + (w>>1)*32 + row;
    dst[(size_t)t*KK + nc] = acc[r];
  }
}

// ---------------- finalize logB, rowmax m_t, btil ----------------
__global__ void __launch_bounds__(256) k_logBall(
    const float* __restrict__ part, const float* __restrict__ mu, const float* __restrict__ dvar,
    const float* __restrict__ cvecT, const float* __restrict__ EdiagT,
    const float* __restrict__ rK, const float* __restrict__ Lhalf, const float* __restrict__ sclK,
    float* __restrict__ logB, float* __restrict__ mrow, float* __restrict__ btil)
{
  extern __shared__ float lds[];
  float* cv = lds; float* ed = lds + DD*KK;
  int tid = threadIdx.x; int k = tid & 63; int w = tid >> 6;
  for (int v = tid; v < DD*KK; v += 256){ cv[v] = cvecT[v]; ed[v] = EdiagT[v]; }
  __syncthreads();
  float rk = rK[k], lh = Lhalf[k], scl = sclK[k];
  int tbase = blockIdx.x*32 + w*8;
  for (int ii = 0; ii < 8; ii++){
    int t = tbase + ii;
    const float* murow = mu   + (size_t)t*DD;
    const float* dvrow = dvar + (size_t)t*DD;
    float a1 = 0.f, a2 = 0.f, ss = 0.f;
    for (int d = 0; d < DD; d++){
      float md = murow[d];
      float vd = fmaxf(dvrow[d], 0.f);
      a1 = fmaf(md, cv[d*KK + k], a1);
      a2 = fmaf(vd, ed[d*KK + k], a2);
      ss = fmaf(md, md, ss);
    }
    float q = scl*ss
            + part[(size_t)0*T_LEN*KK + (size_t)t*KK + k]
            + part[(size_t)1*T_LEN*KK + (size_t)t*KK + k]
            + part[(size_t)2*T_LEN*KK + (size_t)t*KK + k]
            + part[(size_t)3*T_LEN*KK + (size_t)t*KK + k];
    float lb = lh - 0.5f*(q - 2.f*a1 + rk + a2);
    float m  = wred_max(lb);
    logB[(size_t)t*KK + k] = lb;
    btil[(size_t)t*KK + k] = expf(lb - m);
    if (k == 0) mrow[t] = m;
  }
}

// ---------------- pass1: 8-step chunk operators G8 (one wave per chunk) ----------------
#define GROW(r) ((r)*68 + ((((r)>>3)&3)*4))
__global__ void __launch_bounds__(128, 1) k_pass1(const float* __restrict__ Pm,
     const float* __restrict__ btil, float* __restrict__ G8)
{
  __shared__ float lds_s[4352 + 2*4368];
  float* Pl = lds_s;
  int tid = threadIdx.x;
  int w = tid >> 6, lane = tid & 63;
  float* G = lds_s + 4352 + w*4368;
  for (int v = tid; v < 4096; v += 128) Pl[(v>>6)*68 + (v&63)] = Pm[v];
  int chunk = blockIdx.x*2 + w;
  int ti = lane >> 3, tj = lane & 7;
  int r0 = ti*8, c0 = tj*8;
  for (int v = lane; v < 4096; v += 64){
    int i = v >> 6, j = v & 63;
    G[GROW(i) + j] = (i == j) ? 1.f : 0.f;
  }
  __syncthreads();

  for (int s = 0; s < 8; s++){
    int t = chunk*8 + s;
    if (t < 1) continue;
    float acc[8][8];
#pragma unroll
    for (int i = 0; i < 8; i++)
#pragma unroll
      for (int j = 0; j < 8; j++) acc[i][j] = 0.f;
    for (int l = 0; l < 64; l += 4){
      float af[8][4];
#pragma unroll
      for (int i = 0; i < 8; i++){
        float4 x = *(const float4*)&G[GROW(r0+i) + l];
        af[i][0]=x.x; af[i][1]=x.y; af[i][2]=x.z; af[i][3]=x.w;
      }
      float bf[4][8];
#pragma unroll
      for (int q = 0; q < 4; q++){
        float4 y0 = *(const float4*)&Pl[(l+q)*68 + c0];
        float4 y1 = *(const float4*)&Pl[(l+q)*68 + c0 + 4];
        bf[q][0]=y0.x; bf[q][1]=y0.y; bf[q][2]=y0.z; bf[q][3]=y0.w;
        bf[q][4]=y1.x; bf[q][5]=y1.y; bf[q][6]=y1.z; bf[q][7]=y1.w;
      }
#pragma unroll
      for (int q = 0; q < 4; q++)
#pragma unroll
        for (int i = 0; i < 8; i++)
#pragma unroll
          for (int j = 0; j < 8; j++)
            acc[i][j] = fmaf(af[i][q], bf[q][j], acc[i][j]);
    }
    float4 bb0 = *(const float4*)&btil[(size_t)t*KK + c0];
    float4 bb1 = *(const float4*)&btil[(size_t)t*KK + c0 + 4];
    float bj[8] = {bb0.x,bb0.y,bb0.z,bb0.w,bb1.x,bb1.y,bb1.z,bb1.w};
    float mx = 0.f;
#pragma unroll
    for (int i = 0; i < 8; i++)
#pragma unroll
      for (int j = 0; j < 8; j++){ acc[i][j] *= bj[j]; mx = fmaxf(mx, acc[i][j]); }
    mx = wred_max(mx);
    float inv = 1.f/mx;
#pragma unroll
    for (int i = 0; i < 8; i++){
      float4 w0, w1;
      w0.x=acc[i][0]*inv; w0.y=acc[i][1]*inv; w0.z=acc[i][2]*inv; w0.w=acc[i][3]*inv;
      w1.x=acc[i][4]*inv; w1.y=acc[i][5]*inv; w1.z=acc[i][6]*inv; w1.w=acc[i][7]*inv;
      *(float4*)&G[GROW(r0+i) + c0]     = w0;
      *(float4*)&G[GROW(r0+i) + c0 + 4] = w1;
    }
  }
  float* dst = G8 + (size_t)chunk*4096;
  for (int v = lane; v < 4096; v += 64) dst[v] = G[GROW(v>>6) + (v&63)];
}

// ---------------- chain-combine ----------------
__global__ void __launch_bounds__(256, 1) k_chain(const float* __restrict__ src,
        float* __restrict__ dstLin, float* __restrict__ dstLog, int chain)
{
  __shared__ float X[64*68];
  __shared__ float Y[64*68];
  __shared__ float red[256];
  int cb = blockIdx.x, tid = threadIdx.x;
  const float* s0 = src + (size_t)cb*chain*4096;
  for (int v = tid; v < 4096; v += 256) X[(v>>6)*68 + (v&63)] = s0[v];
  int ti = tid >> 4, tj = tid & 15;
  int r0 = ti*4, c0 = tj*4;
  for (int j = 1; j < chain; j++){
    const float* sj = s0 + (size_t)j*4096;
    for (int v = tid; v < 4096; v += 256) Y[(v>>6)*68 + (v&63)] = sj[v];
    __syncthreads();
    float acc[4][4];
#pragma unroll
    for (int i = 0; i < 4; i++)
#pragma unroll
      for (int q = 0; q < 4; q++) acc[i][q] = 0.f;
    for (int l = 0; l < 64; l++){
      float a0 = X[(r0+0)*68 + l], a1 = X[(r0+1)*68 + l];
      float a2 = X[(r0+2)*68 + l], a3 = X[(r0+3)*68 + l];
      float4 yy = *(const float4*)&Y[l*68 + c0];
      acc[0][0]=fmaf(a0,yy.x,acc[0][0]); acc[0][1]=fmaf(a0,yy.y,acc[0][1]); acc[0][2]=fmaf(a0,yy.z,acc[0][2]); acc[0][3]=fmaf(a0,yy.w,acc[0][3]);
      acc[1][0]=fmaf(a1,yy.x,acc[1][0]); acc[1][1]=fmaf(a1,yy.y,acc[1][1]); acc[1][2]=fmaf(a1,yy.z,acc[1][2]); acc[1][3]=fmaf(a1,yy.w,acc[1][3]);
      acc[2][0]=fmaf(a2,yy.x,acc[2][0]); acc[2][1]=fmaf(a2,yy.y,acc[2][1]); acc[2][2]=fmaf(a2,yy.z,acc[2][2]); acc[2][3]=fmaf(a2,yy.w,acc[2][3]);
      acc[3][0]=fmaf(a3,yy.x,acc[3][0]); acc[3][1]=fmaf(a3,yy.y,acc[3][1]); acc[3][2]=fmaf(a3,yy.z,acc[3][2]); acc[3][3]=fmaf(a3,yy.w,acc[3][3]);
    }
    float mx = 0.f;
#pragma unroll
    for (int i = 0; i < 4; i++)
#pragma unroll
      for (int q = 0; q < 4; q++) mx = fmaxf(mx, acc[i][q]);
    red[tid] = mx; __syncthreads();
    for (int off = 128; off > 0; off >>= 1){ if (tid < off) red[tid] = fmaxf(red[tid], red[tid+off]); __syncthreads(); }
    float inv = 1.f/red[0];
    __syncthreads();
#pragma unroll
    for (int i = 0; i < 4; i++){
      float4 wv; wv.x=acc[i][0]*inv; wv.y=acc[i][1]*inv; wv.z=acc[i][2]*inv; wv.w=acc[i][3]*inv;
      *(float4*)&X[(r0+i)*68 + c0] = wv;
    }
    __syncthreads();
  }
  for (int v = tid; v < 4096; v += 256){
    float vv = X[(v>>6)*68 + (v&63)];
    dstLin[(size_t)cb*4096 + v] = vv;
    dstLog[(size_t)cb*4096 + v] = logf(vv);
  }
}

// ---------------- pass2: sequential scan over 64 linear 128-step operators ----------------
__global__ void __launch_bounds__(256, 1) k_pass2(const float* __restrict__ H128,
    const float* __restrict__ logB, const float* __restrict__ log_pi,
    float* __restrict__ aB, float* __restrict__ bB)
{
  __shared__ float Hb[2][64*68];
  __shared__ float sv[64];
  __shared__ float partl[4][64];
  int tid = threadIdx.x;
  int w = tid >> 6, lane = tid & 63;
  bool fwd = (blockIdx.x == 0);
  int nsteps = fwd ? 64 : 63;

  if (w == 0){
    if (fwd){
      float v = log_pi[lane] + logB[lane];
      float m = wred_max(v);
      float e = expf(v - m);
      float s = wred_sum(e);
      sv[lane] = e/s;
    } else {
      sv[lane] = 1.f;
      bB[63*64 + lane] = 1.f;
    }
  }

  int c0i = fwd ? 0 : 63;
  float4 r0, r1, r2, r3;
  {
    const float4* g = (const float4*)(H128 + (size_t)c0i*4096 + tid*16);
    r0 = g[0]; r1 = g[1]; r2 = g[2]; r3 = g[3];
  }
  for (int it = 0; it < nsteps; it++){
    int c = fwd ? it : 63 - it;
    int buf = it & 1;
    if (fwd){
      int i = tid >> 2, cc = (tid & 3)*16;
      *(float4*)&Hb[buf][i*68 + cc + 0]  = r0;
      *(float4*)&Hb[buf][i*68 + cc + 4]  = r1;
      *(float4*)&Hb[buf][i*68 + cc + 8]  = r2;
      *(float4*)&Hb[buf][i*68 + cc + 12] = r3;
    } else {
      int i = tid >> 2, cc = (tid & 3)*16;
      float vals[16] = {r0.x,r0.y,r0.z,r0.w, r1.x,r1.y,r1.z,r1.w,
                        r2.x,r2.y,r2.z,r2.w, r3.x,r3.y,r3.z,r3.w};
#pragma unroll
      for (int q = 0; q < 16; q++) Hb[buf][(cc+q)*68 + i] = vals[q];
    }
    if (it + 1 < nsteps){
      int cn = fwd ? it + 1 : 63 - (it + 1);
      const float4* g = (const float4*)(H128 + (size_t)cn*4096 + tid*16);
      r0 = g[0]; r1 = g[1]; r2 = g[2]; r3 = g[3];
    }
    __syncthreads();
    float p = 0.f;
#pragma unroll
    for (int q = 0; q < 16; q++){
      int i = w*16 + q;
      p = fmaf(sv[i], Hb[buf][i*68 + lane], p);
    }
    partl[w][lane] = p;
    __syncthreads();
    if (w == 0){
      float v = partl[0][lane] + partl[1][lane] + partl[2][lane] + partl[3][lane];
      if (fwd){
        float s = wred_sum(v);
        float a = v/s;
        sv[lane] = a;
        aB[c*64 + lane] = a;
      } else {
        float m = wred_max(v);
        float bb = v/m;
        sv[lane] = bb;
        bB[(c-1)*64 + lane] = bb;
      }
    }
  }
}

// ---------------- pass3: per-64-step-chunk exact recurrences ----------------
__global__ void __launch_bounds__(64, 1) k_pass3(const float* __restrict__ Pm, const float* __restrict__ PTm,
   const float* __restrict__ LH64,
   const float* __restrict__ logB, const float* __restrict__ mrow, const float* __restrict__ btil,
   const float* __restrict__ log_pi,
   const float* __restrict__ aB, const float* __restrict__ bB,
   float* __restrict__ alphahat, float* __restrict__ betahat, float* __restrict__ llpart)
{
  __shared__ float Hl[64*68];
  __shared__ float vl[64];
  int lane = threadIdx.x;
  int bid = blockIdx.x;
  if (bid < 128){
    int c = bid;
    float Preg[64];
#pragma unroll
    for (int i = 0; i < 64; i++) Preg[i] = Pm[i*64 + lane];
    float a; float llacc = 0.f;
    int tstart;
    if (c == 0){
      float v = log_pi[lane] + logB[lane];
      float m = wred_max(v);
      float e = expf(v - m);
      float s = wred_sum(e);
      a = e/s;
      llacc = m + logf(s);
      alphahat[lane] = a;
      tstart = 1;
    } else if (c & 1){
      float lp;
      if (c == 1){
        float v = log_pi[lane] + logB[lane];
        float m = wred_max(v);
        lp = v - m;
      } else {
        lp = logf(aB[((c-1)/2 - 1)*64 + lane]);
      }
      for (int u = lane; u < 1024; u += 64){
        float4 x = ((const float4*)(LH64 + (size_t)(c-1)*4096))[u];
        int row = u >> 4, col = (u & 15)*4;
        *(float4*)&Hl[row*68 + col] = x;
      }
      vl[lane] = lp;
      __syncthreads();
      float mx = -3.0e38f;
      for (int i = 0; i < 64; i++) mx = fmaxf(mx, vl[i] + Hl[i*68 + lane]);
      float s = 0.f;
      for (int i = 0; i < 64; i++) s += expf(vl[i] + Hl[i*68 + lane] - mx);
      float ln = mx + logf(s);
      float mm = wred_max(ln);
      float e  = expf(ln - mm);
      float ss = wred_sum(e);
      a = e/ss;
      __syncthreads();
      tstart = c*64;
    } else {
      a = aB[(c/2 - 1)*64 + lane];
      tstart = c*64;
    }
    int tend = c*64 + 64;
    float bt = btil[(size_t)tstart*KK + lane];
    for (int t = tstart; t < tend; t++){
      float btn = 0.f;
      if (t + 1 < tend) btn = btil[(size_t)(t+1)*KK + lane];
      float mr = mrow[t];
      float p0 = 0.f, p1 = 0.f, p2 = 0.f, p3 = 0.f;
#pragma unroll
      for (int i = 0; i < 16; i++){
        p0 = fmaf(__shfl(a, i,      64), Preg[i],      p0);
        p1 = fmaf(__shfl(a, i + 16, 64), Preg[i + 16], p1);
        p2 = fmaf(__shfl(a, i + 32, 64), Preg[i + 32], p2);
        p3 = fmaf(__shfl(a, i + 48, 64), Preg[i + 48], p3);
      }
      float pred = (p0 + p1) + (p2 + p3);
      float at = pred * bt;
      float s  = wred_sum(at);
      a = at / s;
      llacc += logf(s) + mr;
      alphahat[(size_t)t*KK + lane] = a;
      bt = btn;
    }
    if (lane == 0) llpart[c] = llacc;
  } else {
    int c = bid - 128;
    float PTreg[64];
#pragma unroll
    for (int j = 0; j < 64; j++) PTreg[j] = PTm[j*64 + lane];
    float b, lb;
    if (c == 127){
      b = 1.f; lb = 0.f;
    } else if (c & 1){
      b = bB[((c-1)/2)*64 + lane];
      lb = logf(b);
    } else {
      float lbin = logf(bB[(c/2)*64 + lane]);
      for (int u = lane; u < 1024; u += 64){
        float4 x = ((const float4*)(LH64 + (size_t)(c+1)*4096))[u];
        int row = u >> 4, col = (u & 15)*4;
        Hl[(col+0)*68 + row] = x.x; Hl[(col+1)*68 + row] = x.y;
        Hl[(col+2)*68 + row] = x.z; Hl[(col+3)*68 + row] = x.w;
      }
      vl[lane] = lbin;
      __syncthreads();
      float mx = -3.0e38f;
      for (int j = 0; j < 64; j++) mx = fmaxf(mx, Hl[j*68 + lane] + vl[j]);
      float s = 0.f;
      for (int j = 0; j < 64; j++) s += expf(Hl[j*68 + lane] + vl[j] - mx);
      float ln = mx + logf(s);
      float mm = wred_max(ln);
      lb = ln - mm;
      b = expf(lb);
      __syncthreads();
    }
    int t1 = c*64 + 63;
    betahat[(size_t)t1*KK + lane] = b;
    float lgb = logB[(size_t)t1*KK + lane];
    float mrn = mrow[t1];
    for (int t = t1 - 1; t >= c*64; t--){
      float lgbn = 0.f, mrnn = 0.f;
      if (t > c*64){
        lgbn = logB[(size_t)t*KK + lane];
        mrnn = mrow[t];
      }
      float lv = (lgb - mrn) + lb;
      float vm = wred_max(lv);
      float vv = expf(lv - vm);
      float q0 = 0.f, q1r = 0.f, q2 = 0.f, q3 = 0.f;
#pragma unroll
      for (int j = 0; j < 16; j++){
        q0  = fmaf(PTreg[j],      __shfl(vv, j,      64), q0);
        q1r = fmaf(PTreg[j + 16], __shfl(vv, j + 16, 64), q1r);
        q2  = fmaf(PTreg[j + 32], __shfl(vv, j + 32, 64), q2);
        q3  = fmaf(PTreg[j + 48], __shfl(vv, j + 48, 64), q3);
      }
      float bn = (q0 + q1r) + (q2 + q3);
      float bmax = wred_max(bn);
      b = bn / bmax;
      lb = logf(b);
      betahat[(size_t)t*KK + lane] = b;
      lgb = lgbn; mrn = mrnn;
    }
  }
}

// ---------------- outputs ----------------
__global__ void k_out_rhat(const float* __restrict__ ah, const float* __restrict__ bh,
                           float* __restrict__ out){
  int tid = threadIdx.x; int w = tid >> 6, lane = tid & 63;
  int t = blockIdx.x*4 + w;
  float la = logf(ah[(size_t)t*KK + lane]);
  float lb = logf(bh[(size_t)t*KK + lane]);
  float s = la + lb;
  float m = wred_max(s);
  float p = (m < -3.0e37f) ? 1.f : expf(s - m);
  float ss = wred_sum(p);
  out[(size_t)t*KK + lane] = p/ss;
}

__global__ void __launch_bounds__(256) k_out_xi(const float* __restrict__ ah,
     const float* __restrict__ bh, const float* __restrict__ ElogA,
     const float* __restrict__ logB, float* __restrict__ out)
{
  __shared__ float la[64], wc[64];
  __shared__ float redm[4], reds[4];
  int tid = threadIdx.x;
  int t = blockIdx.x + 1;
  if (tid < 64) la[tid] = logf(ah[(size_t)(t-1)*KK + tid]);
  else if (tid < 128){
    int j = tid - 64;
    wc[j] = logB[(size_t)t*KK + j] + logf(bh[(size_t)t*KK + j]);
  }
  __syncthreads();
  int r = tid >> 6, j = tid & 63;
  float sv[16];
  float mx = -3.0e38f;
#pragma unroll
  for (int n = 0; n < 16; n++){
    int i = r + n*4;
    float s = la[i] + ElogA[i*KK + j] + wc[j];
    sv[n] = s;
    mx = fmaxf(mx, s);
  }
  float mxw = wred_max(mx);
  if ((tid & 63) == 0) redm[tid >> 6] = mxw;
  __syncthreads();
  float m = fmaxf(fmaxf(redm[0], redm[1]), fmaxf(redm[2], redm[3]));
  bool degen = !(m > -3.0e37f);
  float pv[16]; float ps = 0.f;
#pragma unroll
  for (int n = 0; n < 16; n++){
    float p = degen ? 1.f : expf(sv[n] - m);
    pv[n] = p; ps += p;
  }
  float psw = wred_sum(ps);
  if ((tid & 63) == 0) reds[tid >> 6] = psw;
  __syncthreads();
  float inv = 1.f/(reds[0] + reds[1] + reds[2] + reds[3]);
  float* dst = out + (size_t)(t-1)*4096;
#pragma unroll
  for (int n = 0; n < 16; n++){
    int i = r + n*4;
    dst[i*KK + j] = pv[n]*inv;
  }
}

__global__ void k_ll(const float* __restrict__ llpart, float* __restrict__ out){
  __shared__ float red[128];
  int tid = threadIdx.x;
  red[tid] = llpart[tid];
  __syncthreads();
  for (int off = 64; off > 0; off >>= 1){ if (tid < off) red[tid] += red[tid+off]; __syncthreads(); }
  if (tid == 0) out[0] = red[0];
}

extern "C" void kernel_launch(void* const* d_in, const int* in_sizes, int n_in,
                              void* d_out, int out_size, void* d_ws, size_t ws_size,
                              hipStream_t stream)
{
  const float* mu    = (const float*)d_in[0];
  const float* dvar  = (const float*)d_in[1];
  const float* niwmu = (const float*)d_in[2];
  const float* Psi   = (const float*)d_in[3];
  const float* nu    = (const float*)d_in[4];
  const float* phi   = (const float*)d_in[5];
  const float* lpi   = (const float*)d_in[6];
  float* out = (float*)d_out;
  float* ws  = (float*)d_ws;

  size_t o = 0;
  float* EbfF   = ws + o; o += (size_t)DD*DD*KK/2;
  float* EdiagT = ws + o; o += (size_t)DD*KK;
  float* cvecT  = ws + o; o += (size_t)DD*KK;
  float* rK     = ws + o; o += KK;
  float* Lhalf  = ws + o; o += KK;
  float* sclK   = ws + o; o += KK;
  float* ElogA  = ws + o; o += KK*KK;
  float* P      = ws + o; o += KK*KK;
  float* PT     = ws + o; o += KK*KK;
  float* logB   = ws + o; o += (size_t)T_LEN*KK;
  float* mrowp  = ws + o; o += T_LEN;
  float* btil   = ws + o; o += (size_t)T_LEN*KK;
  float* G8     = ws + o; o += (size_t)1024*4096;
  float* H64    = ws + o; o += (size_t)128*4096;
  float* LH64   = ws + o; o += (size_t)128*4096;
  float* H128   = ws + o; o += (size_t)64*4096;
  float* LH128  = ws + o; o += (size_t)64*4096;
  float* aB     = ws + o; o += 64*64;
  float* bB     = ws + o; o += 64*64;
  float* llp    = ws + o; o += 128;
  float* ah     = ws + o; o += (size_t)T_LEN*KK;
  float* bh     = ws + o; o += (size_t)T_LEN*KK;
  if (ws_size < o*sizeof(float)) return;

  __bf16* Ebf = (__bf16*)EbfF;
  float*  part = G8;

  hipFuncSetAttribute((const void*)k_neumann, hipFuncAttributeMaxDynamicSharedMemorySize, 2*DD*RS*4);
  hipFuncSetAttribute((const void*)k_logBall, hipFuncAttributeMaxDynamicSharedMemorySize, 2*DD*KK*4);

  k_elog<<<64, 64, 0, stream>>>(phi, ElogA, P, PT);
  k_neumann<<<64, 256, 2*DD*RS*4, stream>>>(Psi, niwmu, nu, Ebf, EdiagT, cvecT, rK, Lhalf, sclK);
  k_q1<<<512, 256, 0, stream>>>(mu, Ebf, part);
  k_logBall<<<256, 256, 2*DD*KK*4, stream>>>(part, mu, dvar, cvecT, EdiagT, rK, Lhalf, sclK, logB, mrowp, btil);
  k_pass1<<<512, 128, 0, stream>>>(P, btil, G8);
  k_chain<<<128, 256, 0, stream>>>(G8, H64, LH64, 8);
  k_chain<<<64, 256, 0, stream>>>(H64, H128, LH128, 2);
  k_pass2<<<2, 256, 0, stream>>>(H128, logB, lpi, aB, bB);
  k_pass3<<<256, 64, 0, stream>>>(P, PT, LH64, logB, mrowp, btil, lpi, aB, bB, ah, bh, llp);
  k_out_rhat<<<2048, 256, 0, stream>>>(ah, bh, out);
  k_out_xi<<<T_LEN-1, 256, 0, stream>>>(ah, bh, ElogA, logB, out + (size_t)T_LEN*KK);
  k_ll<<<1, 128, 0, stream>>>(llp, out + (size_t)T_LEN*KK + (size_t)(T_LEN-1)*KK*KK);
}

// Round 4
// 501.695 us; speedup vs baseline: 3.1473x; 1.2481x over previous
//
#include <hip/hip_runtime.h>
#include <math.h>

#define T_LEN 8192
#define KK 64
#define DD 128
#define RS 132
#define MUPB 136
#define GP 68

typedef __bf16  bf16x4 __attribute__((ext_vector_type(4)));
typedef __bf16  bf16x8 __attribute__((ext_vector_type(8)));
typedef float  f32x16 __attribute__((ext_vector_type(16)));

__device__ __forceinline__ float wred_max(float v){
#pragma unroll
  for (int m = 1; m < 64; m <<= 1) v = fmaxf(v, __shfl_xor(v, m, 64));
  return v;
}
__device__ __forceinline__ float wred_sum(float v){
#pragma unroll
  for (int m = 1; m < 64; m <<= 1) v += __shfl_xor(v, m, 64);
  return v;
}
__device__ __forceinline__ float digamma_f(float x){
  float r = 0.f;
  while (x < 6.f){ r -= 1.f/x; x += 1.f; }
  float ix = 1.f/x, ix2 = ix*ix;
  return r + logf(x) - 0.5f*ix - ix2*(0.0833333333f - ix2*(0.0083333333f - ix2*0.0039682540f));
}

// ---------------- Neumann inverse + logdet + ElogA/P/PT (elog folded in) ----------------
__global__ void __launch_bounds__(256, 1) k_neumann(
    const float* __restrict__ Psi, const float* __restrict__ niw_mu,
    const float* __restrict__ nu_, const float* __restrict__ phi,
    __bf16* __restrict__ Ebf, float* __restrict__ EdiagT,
    float* __restrict__ cvecT, float* __restrict__ rK, float* __restrict__ Lhalf,
    float* __restrict__ sclK,
    float* __restrict__ ElogA, float* __restrict__ P, float* __restrict__ PT)
{
  extern __shared__ float lds[];
  float* Rl = lds;            // [DD][RS]
  float* Pb = lds + DD*RS;    // [DD][RS] (holds S at the end)
  __shared__ float red[256];
  __shared__ float msh[DD];
  int k = blockIdx.x, tid = threadIdx.x;
  const float* A = Psi + (size_t)k*DD*DD;

  // folded k_elog: wave 0 handles row k of phi
  if (tid < 64){
    float ph = phi[k*KK + tid];
    float s  = wred_sum(ph);
    float e  = digamma_f(ph) - digamma_f(s);
    ElogA[k*KK + tid] = e;
    float p = expf(e);
    P [k*KK + tid] = p;
    PT[tid*KK + k] = p;
  }

  float tl = 0.f;
  for (int d = tid; d < DD; d += 256) tl += A[d*DD + d];
  red[tid] = tl; __syncthreads();
  for (int off = 128; off > 0; off >>= 1){ if (tid < off) red[tid] += red[tid+off]; __syncthreads(); }
  float c = red[0] / (float)DD;
  __syncthreads();

  float trpow = 0.f;
  for (int idx = tid; idx < DD*DD; idx += 256){
    int d = idx >> 7, e = idx & 127;
    float v = ((d == e) ? 1.f : 0.f) - A[idx]/c;
    Rl[d*RS + e] = v;
    if (d == e) trpow += v;
  }
  __syncthreads();

  int tr = tid >> 4, tc = tid & 15;
  int r0 = tr*8, c0 = tc*8;
  float S[8][8];
#pragma unroll
  for (int i = 0; i < 8; i++)
#pragma unroll
    for (int j = 0; j < 8; j++){
      float v = Rl[(r0+i)*RS + c0+j];
      if (r0+i == c0+j) v += 1.f;
      S[i][j] = v;
    }

  // Cc = R*R (single Neumann term; |R|<=0.025 so R^3 truncation ~1.6e-5 rel)
  {
    float Cc[8][8];
#pragma unroll
    for (int i = 0; i < 8; i++)
#pragma unroll
      for (int j = 0; j < 8; j++) Cc[i][j] = 0.f;
    for (int l = 0; l < DD; l += 4){
      float af[4][8], bf[4][8];
#pragma unroll
      for (int q = 0; q < 4; q++){
        float4 x0 = *(const float4*)&Rl[(l+q)*RS + r0];
        float4 x1 = *(const float4*)&Rl[(l+q)*RS + r0 + 4];
        af[q][0]=x0.x; af[q][1]=x0.y; af[q][2]=x0.z; af[q][3]=x0.w;
        af[q][4]=x1.x; af[q][5]=x1.y; af[q][6]=x1.z; af[q][7]=x1.w;
        float4 y0 = *(const float4*)&Rl[(l+q)*RS + c0];
        float4 y1 = *(const float4*)&Rl[(l+q)*RS + c0 + 4];
        bf[q][0]=y0.x; bf[q][1]=y0.y; bf[q][2]=y0.z; bf[q][3]=y0.w;
        bf[q][4]=y1.x; bf[q][5]=y1.y; bf[q][6]=y1.z; bf[q][7]=y1.w;
      }
#pragma unroll
      for (int q = 0; q < 4; q++)
#pragma unroll
        for (int i = 0; i < 8; i++)
#pragma unroll
          for (int j = 0; j < 8; j++)
            Cc[i][j] = fmaf(af[q][i], bf[q][j], Cc[i][j]);
    }
#pragma unroll
    for (int i = 0; i < 8; i++)
#pragma unroll
      for (int j = 0; j < 8; j++) S[i][j] += Cc[i][j];
    if (tr == tc){
#pragma unroll
      for (int i = 0; i < 8; i++) trpow += Cc[i][i]*0.5f;
    }
  }

  red[tid] = trpow; __syncthreads();
  for (int off = 128; off > 0; off >>= 1){ if (tid < off) red[tid] += red[tid+off]; __syncthreads(); }
  float trsum = red[0];
  __syncthreads();

  float nu = nu_[k];
  float dl = 0.f;
  for (int i = tid; i < DD; i += 256) dl += digamma_f((nu - (float)i)*0.5f);
  red[tid] = dl; __syncthreads();
  for (int off = 128; off > 0; off >>= 1){ if (tid < off) red[tid] += red[tid+off]; __syncthreads(); }
  if (tid == 0){
    float logdetPsi = (float)DD*logf(c) - trsum;
    float Elogdet = red[0] + (float)DD*0.69314718056f - logdetPsi;
    Lhalf[k] = 0.5f*Elogdet - 0.5f*(float)DD*1.83787706641f;
    sclK[k]  = nu / c;
  }
  __syncthreads();

  float scl = nu / c;
#pragma unroll
  for (int i = 0; i < 8; i++)
#pragma unroll
    for (int j = 0; j < 8; j++){
      float sv = S[i][j];
      bool dg = (r0+i == c0+j);
      if (dg) EdiagT[(r0+i)*KK + k] = scl*sv;
      float et = scl*(sv - (dg ? 1.f : 0.f));
      int r = (r0+i)*DD + (c0+j);
      Ebf[(size_t)(r>>4)*1024 + k*16 + (r&15)] = (__bf16)et;
    }
#pragma unroll
  for (int i = 0; i < 8; i++){
    float4 w0, w1;
    w0.x=S[i][0]; w0.y=S[i][1]; w0.z=S[i][2]; w0.w=S[i][3];
    w1.x=S[i][4]; w1.y=S[i][5]; w1.z=S[i][6]; w1.w=S[i][7];
    *(float4*)&Pb[(r0+i)*RS + c0]     = w0;
    *(float4*)&Pb[(r0+i)*RS + c0 + 4] = w1;
  }
  for (int d = tid; d < DD; d += 256) msh[d] = niw_mu[k*DD + d];
  __syncthreads();
  float cv = 0.f;
  if (tid < DD){
    float acc = 0.f;
    for (int e = 0; e < DD; e++) acc += Pb[tid*RS + e]*msh[e];
    cv = scl*acc;
    cvecT[tid*KK + k] = cv;
  }
  red[tid] = (tid < DD) ? msh[tid]*cv : 0.f; __syncthreads();
  for (int off = 128; off > 0; off >>= 1){ if (tid < off) red[tid] += red[tid+off]; __syncthreads(); }
  if (tid == 0) rK[k] = red[0];
}

// ---------------- residual quad GEMM (4-panel grouped double buffer) ----------------
__global__ void __launch_bounds__(256) k_q1(const float* __restrict__ mu,
      const __bf16* __restrict__ Ebf, float* __restrict__ part)
{
  __shared__ __bf16 muL[64*MUPB];
  __shared__ __bf16 Bp[2][4][64*24];
  int b = blockIdx.x;
  int rs = b & 3, tseg = b >> 2;
  int t0 = tseg*64, d0 = rs*32;
  int tid = threadIdx.x;
  int w = tid >> 6, lane = tid & 63;
  int tl = (w>>1)*32 + (lane&31);
  int nc = (w&1)*32 + (lane&31);
  int k0 = (lane>>5)*8;

  for (int v = tid; v < 64*32; v += 256){
    int t = v >> 5, seg = v & 31;
    float4 x = *(const float4*)&mu[(size_t)(t0+t)*DD + seg*4];
    bf16x4 hv;
    hv[0] = (__bf16)x.x; hv[1] = (__bf16)x.y; hv[2] = (__bf16)x.z; hv[3] = (__bf16)x.w;
    *(bf16x4*)&muL[t*MUPB + seg*4] = hv;
  }
  {
    const unsigned long long* gp = (const unsigned long long*)(Ebf + (size_t)(d0*8)*1024);
#pragma unroll
    for (int q = 0; q < 4; q++){
      unsigned long long v = gp[q*256 + tid];
      *((unsigned long long*)&Bp[0][q][(tid>>2)*24 + (tid&3)*4]) = v;
    }
  }
  __syncthreads();

  f32x16 acc;
#pragma unroll
  for (int i = 0; i < 16; i++) acc[i] = 0.f;

  for (int ss = 0; ss < 64; ss++){
    unsigned long long pre[4];
    bool more = (ss < 63);
    if (more){
      const unsigned long long* gp = (const unsigned long long*)(Ebf + (size_t)(d0*8 + (ss+1)*4)*1024);
#pragma unroll
      for (int q = 0; q < 4; q++) pre[q] = gp[q*256 + tid];
    }
#pragma unroll
    for (int q = 0; q < 4; q++){
      int s = ss*4 + q;
      int d = d0 + (s>>3), e0 = (s&7)<<4;
      float mud = (float)muL[tl*MUPB + d];
      bf16x8 mv = *(const bf16x8*)&muL[tl*MUPB + e0 + k0];
      bf16x8 af;
#pragma unroll
      for (int j = 0; j < 8; j++) af[j] = (__bf16)(mud * (float)mv[j]);
      bf16x8 bfr = *(const bf16x8*)&Bp[ss&1][q][nc*24 + k0];
      acc = __builtin_amdgcn_mfma_f32_32x32x16_bf16(af, bfr, acc, 0, 0, 0);
    }
    if (more){
#pragma unroll
      for (int q = 0; q < 4; q++)
        *((unsigned long long*)&Bp[(ss+1)&1][q][(tid>>2)*24 + (tid&3)*4]) = pre[q];
    }
    __syncthreads();
  }

  float* dst = part + (size_t)rs*T_LEN*KK;
#pragma unroll
  for (int r = 0; r < 16; r++){
    int row = (r&3) + 8*(r>>2) + 4*(lane>>5);
    int t = t0 + (w>>1)*32 + row;
    dst[(size_t)t*KK + nc] = acc[r];
  }
}

// ---------------- finalize logB, rowmax m_t, btil ----------------
__global__ void __launch_bounds__(256) k_logBall(
    const float* __restrict__ part, const float* __restrict__ mu, const float* __restrict__ dvar,
    const float* __restrict__ cvecT, const float* __restrict__ EdiagT,
    const float* __restrict__ rK, const float* __restrict__ Lhalf, const float* __restrict__ sclK,
    float* __restrict__ logB, float* __restrict__ mrow, float* __restrict__ btil)
{
  extern __shared__ float lds[];
  float* cv = lds; float* ed = lds + DD*KK;
  int tid = threadIdx.x; int k = tid & 63; int w = tid >> 6;
  for (int v = tid; v < DD*KK; v += 256){ cv[v] = cvecT[v]; ed[v] = EdiagT[v]; }
  __syncthreads();
  float rk = rK[k], lh = Lhalf[k], scl = sclK[k];
  int tbase = blockIdx.x*32 + w*8;
  for (int ii = 0; ii < 8; ii++){
    int t = tbase + ii;
    const float* murow = mu   + (size_t)t*DD;
    const float* dvrow = dvar + (size_t)t*DD;
    float a1 = 0.f, a2 = 0.f, ss = 0.f;
    for (int d = 0; d < DD; d++){
      float md = murow[d];
      float vd = fmaxf(dvrow[d], 0.f);
      a1 = fmaf(md, cv[d*KK + k], a1);
      a2 = fmaf(vd, ed[d*KK + k], a2);
      ss = fmaf(md, md, ss);
    }
    float q = scl*ss
            + part[(size_t)0*T_LEN*KK + (size_t)t*KK + k]
            + part[(size_t)1*T_LEN*KK + (size_t)t*KK + k]
            + part[(size_t)2*T_LEN*KK + (size_t)t*KK + k]
            + part[(size_t)3*T_LEN*KK + (size_t)t*KK + k];
    float lb = lh - 0.5f*(q - 2.f*a1 + rk + a2);
    float m  = wred_max(lb);
    logB[(size_t)t*KK + k] = lb;
    btil[(size_t)t*KK + k] = expf(lb - m);
    if (k == 0) mrow[t] = m;
  }
}

// ---------------- pass1: 8-step chunk operators via bf16 hi/lo MFMA ----------------
// One block (2 waves) per chunk. G fp32 in LDS [64][GP]; each wave owns 32 rows.
__global__ void __launch_bounds__(128, 1) k_pass1(const float* __restrict__ Pm,
     const float* __restrict__ btil, float* __restrict__ G8)
{
  __shared__ float G[64*GP];
  __shared__ float wmax[2][2];
  int tid = threadIdx.x, w = tid >> 6, lane = tid & 63;
  int chunk = blockIdx.x;
  int kb8 = (lane >> 5)*8;
  int n = lane & 31;

  // B fragments (P hi/lo), step-invariant, kept in VGPRs
  bf16x8 Bhi[4][2], Blo[4][2];
#pragma unroll
  for (int Kb = 0; Kb < 4; Kb++)
#pragma unroll
    for (int J = 0; J < 2; J++){
#pragma unroll
      for (int j = 0; j < 8; j++){
        float p = Pm[(Kb*16 + kb8 + j)*KK + J*32 + n];
        __bf16 h = (__bf16)p;
        Bhi[Kb][J][j] = h;
        Blo[Kb][J][j] = (__bf16)(p - (float)h);
      }
    }
  for (int v = tid; v < 64*64; v += 128){
    int i = v >> 6, j = v & 63;
    G[i*GP + j] = (i == j) ? 1.f : 0.f;
  }
  __syncthreads();

  int m = w*32 + n;     // A-row this lane reads (own half)
  for (int s = 0; s < 8; s++){
    int t = chunk*8 + s;
    if (t >= 1){
      f32x16 acc0, acc1;
#pragma unroll
      for (int i = 0; i < 16; i++){ acc0[i] = 0.f; acc1[i] = 0.f; }
#pragma unroll
      for (int Kb = 0; Kb < 4; Kb++){
        float4 x0 = *(const float4*)&G[m*GP + Kb*16 + kb8];
        float4 x1 = *(const float4*)&G[m*GP + Kb*16 + kb8 + 4];
        float xv[8] = {x0.x,x0.y,x0.z,x0.w,x1.x,x1.y,x1.z,x1.w};
        bf16x8 ah, al;
#pragma unroll
        for (int j = 0; j < 8; j++){
          __bf16 h = (__bf16)xv[j];
          ah[j] = h;
          al[j] = (__bf16)(xv[j] - (float)h);
        }
        acc0 = __builtin_amdgcn_mfma_f32_32x32x16_bf16(ah, Bhi[Kb][0], acc0, 0,0,0);
        acc0 = __builtin_amdgcn_mfma_f32_32x32x16_bf16(ah, Blo[Kb][0], acc0, 0,0,0);
        acc0 = __builtin_amdgcn_mfma_f32_32x32x16_bf16(al, Bhi[Kb][0], acc0, 0,0,0);
        acc1 = __builtin_amdgcn_mfma_f32_32x32x16_bf16(ah, Bhi[Kb][1], acc1, 0,0,0);
        acc1 = __builtin_amdgcn_mfma_f32_32x32x16_bf16(ah, Blo[Kb][1], acc1, 0,0,0);
        acc1 = __builtin_amdgcn_mfma_f32_32x32x16_bf16(al, Bhi[Kb][1], acc1, 0,0,0);
      }
      float b0 = btil[(size_t)t*KK + n];
      float b1 = btil[(size_t)t*KK + 32 + n];
      float mx = 0.f;
#pragma unroll
      for (int i = 0; i < 16; i++){
        acc0[i] *= b0; acc1[i] *= b1;
        mx = fmaxf(mx, fmaxf(acc0[i], acc1[i]));
      }
      mx = wred_max(mx);
      if (lane == 0) wmax[s&1][w] = mx;
      __syncthreads();
      float inv = 1.f/fmaxf(wmax[s&1][0], wmax[s&1][1]);
#pragma unroll
      for (int r = 0; r < 16; r++){
        int row = w*32 + (r&3) + 8*(r>>2) + 4*(lane>>5);
        G[row*GP + n]      = acc0[r]*inv;
        G[row*GP + 32 + n] = acc1[r]*inv;
      }
    }
  }
  __syncthreads();
  float* dst = G8 + (size_t)chunk*4096;
  for (int v = tid; v < 4096; v += 128) dst[v] = G[(v>>6)*GP + (v&63)];
}

// ---------------- chain-combine ----------------
__global__ void __launch_bounds__(256, 1) k_chain(const float* __restrict__ src,
        float* __restrict__ dstLin, float* __restrict__ dstLog, int chain)
{
  __shared__ float X[64*68];
  __shared__ float Y[64*68];
  __shared__ float red[256];
  int cb = blockIdx.x, tid = threadIdx.x;
  const float* s0 = src + (size_t)cb*chain*4096;
  for (int v = tid; v < 4096; v += 256) X[(v>>6)*68 + (v&63)] = s0[v];
  int ti = tid >> 4, tj = tid & 15;
  int r0 = ti*4, c0 = tj*4;
  for (int j = 1; j < chain; j++){
    const float* sj = s0 + (size_t)j*4096;
    for (int v = tid; v < 4096; v += 256) Y[(v>>6)*68 + (v&63)] = sj[v];
    __syncthreads();
    float acc[4][4];
#pragma unroll
    for (int i = 0; i < 4; i++)
#pragma unroll
      for (int q = 0; q < 4; q++) acc[i][q] = 0.f;
    for (int l = 0; l < 64; l++){
      float a0 = X[(r0+0)*68 + l], a1 = X[(r0+1)*68 + l];
      float a2 = X[(r0+2)*68 + l], a3 = X[(r0+3)*68 + l];
      float4 yy = *(const float4*)&Y[l*68 + c0];
      acc[0][0]=fmaf(a0,yy.x,acc[0][0]); acc[0][1]=fmaf(a0,yy.y,acc[0][1]); acc[0][2]=fmaf(a0,yy.z,acc[0][2]); acc[0][3]=fmaf(a0,yy.w,acc[0][3]);
      acc[1][0]=fmaf(a1,yy.x,acc[1][0]); acc[1][1]=fmaf(a1,yy.y,acc[1][1]); acc[1][2]=fmaf(a1,yy.z,acc[1][2]); acc[1][3]=fmaf(a1,yy.w,acc[1][3]);
      acc[2][0]=fmaf(a2,yy.x,acc[2][0]); acc[2][1]=fmaf(a2,yy.y,acc[2][1]); acc[2][2]=fmaf(a2,yy.z,acc[2][2]); acc[2][3]=fmaf(a2,yy.w,acc[2][3]);
      acc[3][0]=fmaf(a3,yy.x,acc[3][0]); acc[3][1]=fmaf(a3,yy.y,acc[3][1]); acc[3][2]=fmaf(a3,yy.z,acc[3][2]); acc[3][3]=fmaf(a3,yy.w,acc[3][3]);
    }
    float mx = 0.f;
#pragma unroll
    for (int i = 0; i < 4; i++)
#pragma unroll
      for (int q = 0; q < 4; q++) mx = fmaxf(mx, acc[i][q]);
    red[tid] = mx; __syncthreads();
    for (int off = 128; off > 0; off >>= 1){ if (tid < off) red[tid] = fmaxf(red[tid], red[tid+off]); __syncthreads(); }
    float inv = 1.f/red[0];
    __syncthreads();
#pragma unroll
    for (int i = 0; i < 4; i++){
      float4 wv; wv.x=acc[i][0]*inv; wv.y=acc[i][1]*inv; wv.z=acc[i][2]*inv; wv.w=acc[i][3]*inv;
      *(float4*)&X[(r0+i)*68 + c0] = wv;
    }
    __syncthreads();
  }
  for (int v = tid; v < 4096; v += 256){
    float vv = X[(v>>6)*68 + (v&63)];
    dstLin[(size_t)cb*4096 + v] = vv;
    dstLog[(size_t)cb*4096 + v] = logf(vv);
  }
}

// ---------------- pass2: sequential scan over 64 linear 128-step operators ----------------
__global__ void __launch_bounds__(256, 1) k_pass2(const float* __restrict__ H128,
    const float* __restrict__ logB, const float* __restrict__ log_pi,
    float* __restrict__ aB, float* __restrict__ bB)
{
  __shared__ float Hb[2][64*68];
  __shared__ float sv[64];
  __shared__ float partl[4][64];
  int tid = threadIdx.x;
  int w = tid >> 6, lane = tid & 63;
  bool fwd = (blockIdx.x == 0);
  int nsteps = fwd ? 64 : 63;

  if (w == 0){
    if (fwd){
      float v = log_pi[lane] + logB[lane];
      float m = wred_max(v);
      float e = expf(v - m);
      float s = wred_sum(e);
      sv[lane] = e/s;
    } else {
      sv[lane] = 1.f;
      bB[63*64 + lane] = 1.f;
    }
  }

  int c0i = fwd ? 0 : 63;
  float4 r0, r1, r2, r3;
  {
    const float4* g = (const float4*)(H128 + (size_t)c0i*4096 + tid*16);
    r0 = g[0]; r1 = g[1]; r2 = g[2]; r3 = g[3];
  }
  for (int it = 0; it < nsteps; it++){
    int c = fwd ? it : 63 - it;
    int buf = it & 1;
    if (fwd){
      int i = tid >> 2, cc = (tid & 3)*16;
      *(float4*)&Hb[buf][i*68 + cc + 0]  = r0;
      *(float4*)&Hb[buf][i*68 + cc + 4]  = r1;
      *(float4*)&Hb[buf][i*68 + cc + 8]  = r2;
      *(float4*)&Hb[buf][i*68 + cc + 12] = r3;
    } else {
      int i = tid >> 2, cc = (tid & 3)*16;
      float vals[16] = {r0.x,r0.y,r0.z,r0.w, r1.x,r1.y,r1.z,r1.w,
                        r2.x,r2.y,r2.z,r2.w, r3.x,r3.y,r3.z,r3.w};
#pragma unroll
      for (int q = 0; q < 16; q++) Hb[buf][(cc+q)*68 + i] = vals[q];
    }
    if (it + 1 < nsteps){
      int cn = fwd ? it + 1 : 63 - (it + 1);
      const float4* g = (const float4*)(H128 + (size_t)cn*4096 + tid*16);
      r0 = g[0]; r1 = g[1]; r2 = g[2]; r3 = g[3];
    }
    __syncthreads();
    float p = 0.f;
#pragma unroll
    for (int q = 0; q < 16; q++){
      int i = w*16 + q;
      p = fmaf(sv[i], Hb[buf][i*68 + lane], p);
    }
    partl[w][lane] = p;
    __syncthreads();
    if (w == 0){
      float v = partl[0][lane] + partl[1][lane] + partl[2][lane] + partl[3][lane];
      if (fwd){
        float s = wred_sum(v);
        float a = v/s;
        sv[lane] = a;
        aB[c*64 + lane] = a;
      } else {
        float m = wred_max(v);
        float bb = v/m;
        sv[lane] = bb;
        bB[(c-1)*64 + lane] = bb;
      }
    }
  }
}

// ---------------- pass3: per-64-step-chunk exact recurrences ----------------
__global__ void __launch_bounds__(64, 1) k_pass3(const float* __restrict__ Pm, const float* __restrict__ PTm,
   const float* __restrict__ LH64,
   const float* __restrict__ logB, const float* __restrict__ mrow, const float* __restrict__ btil,
   const float* __restrict__ log_pi,
   const float* __restrict__ aB, const float* __restrict__ bB,
   float* __restrict__ alphahat, float* __restrict__ betahat, float* __restrict__ llpart)
{
  __shared__ float Hl[64*68];
  __shared__ float vl[64];
  int lane = threadIdx.x;
  int bid = blockIdx.x;
  if (bid < 128){
    int c = bid;
    float Preg[64];
#pragma unroll
    for (int i = 0; i < 64; i++) Preg[i] = Pm[i*64 + lane];
    float a; float llacc = 0.f;
    int tstart;
    if (c == 0){
      float v = log_pi[lane] + logB[lane];
      float m = wred_max(v);
      float e = expf(v - m);
      float s = wred_sum(e);
      a = e/s;
      llacc = m + logf(s);
      alphahat[lane] = a;
      tstart = 1;
    } else if (c & 1){
      float lp;
      if (c == 1){
        float v = log_pi[lane] + logB[lane];
        float m = wred_max(v);
        lp = v - m;
      } else {
        lp = logf(aB[((c-1)/2 - 1)*64 + lane]);
      }
      for (int u = lane; u < 1024; u += 64){
        float4 x = ((const float4*)(LH64 + (size_t)(c-1)*4096))[u];
        int row = u >> 4, col = (u & 15)*4;
        *(float4*)&Hl[row*68 + col] = x;
      }
      vl[lane] = lp;
      __syncthreads();
      float mx = -3.0e38f;
      for (int i = 0; i < 64; i++) mx = fmaxf(mx, vl[i] + Hl[i*68 + lane]);
      float s = 0.f;
      for (int i = 0; i < 64; i++) s += expf(vl[i] + Hl[i*68 + lane] - mx);
      float ln = mx + logf(s);
      float mm = wred_max(ln);
      float e  = expf(ln - mm);
      float ss = wred_sum(e);
      a = e/ss;
      __syncthreads();
      tstart = c*64;
    } else {
      a = aB[(c/2 - 1)*64 + lane];
      tstart = c*64;
    }
    int tend = c*64 + 64;
    float bt = btil[(size_t)tstart*KK + lane];
    for (int t = tstart; t < tend; t++){
      float btn = 0.f;
      if (t + 1 < tend) btn = btil[(size_t)(t+1)*KK + lane];
      float mr = mrow[t];
      float p0 = 0.f, p1 = 0.f, p2 = 0.f, p3 = 0.f;
#pragma unroll
      for (int i = 0; i < 16; i++){
        p0 = fmaf(__shfl(a, i,      64), Preg[i],      p0);
        p1 = fmaf(__shfl(a, i + 16, 64), Preg[i + 16], p1);
        p2 = fmaf(__shfl(a, i + 32, 64), Preg[i + 32], p2);
        p3 = fmaf(__shfl(a, i + 48, 64), Preg[i + 48], p3);
      }
      float pred = (p0 + p1) + (p2 + p3);
      float at = pred * bt;
      float s  = wred_sum(at);
      a = at / s;
      llacc += logf(s) + mr;
      alphahat[(size_t)t*KK + lane] = a;
      bt = btn;
    }
    if (lane == 0) llpart[c] = llacc;
  } else {
    int c = bid - 128;
    float PTreg[64];
#pragma unroll
    for (int j = 0; j < 64; j++) PTreg[j] = PTm[j*64 + lane];
    float b, lb;
    if (c == 127){
      b = 1.f; lb = 0.f;
    } else if (c & 1){
      b = bB[((c-1)/2)*64 + lane];
      lb = logf(b);
    } else {
      float lbin = logf(bB[(c/2)*64 + lane]);
      for (int u = lane; u < 1024; u += 64){
        float4 x = ((const float4*)(LH64 + (size_t)(c+1)*4096))[u];
        int row = u >> 4, col = (u & 15)*4;
        Hl[(col+0)*68 + row] = x.x; Hl[(col+1)*68 + row] = x.y;
        Hl[(col+2)*68 + row] = x.z; Hl[(col+3)*68 + row] = x.w;
      }
      vl[lane] = lbin;
      __syncthreads();
      float mx = -3.0e38f;
      for (int j = 0; j < 64; j++) mx = fmaxf(mx, Hl[j*68 + lane] + vl[j]);
      float s = 0.f;
      for (int j = 0; j < 64; j++) s += expf(Hl[j*68 + lane] + vl[j] - mx);
      float ln = mx + logf(s);
      float mm = wred_max(ln);
      lb = ln - mm;
      b = expf(lb);
      __syncthreads();
    }
    int t1 = c*64 + 63;
    betahat[(size_t)t1*KK + lane] = b;
    float lgb = logB[(size_t)t1*KK + lane];
    float mrn = mrow[t1];
    for (int t = t1 - 1; t >= c*64; t--){
      float lgbn = 0.f, mrnn = 0.f;
      if (t > c*64){
        lgbn = logB[(size_t)t*KK + lane];
        mrnn = mrow[t];
      }
      float lv = (lgb - mrn) + lb;
      float vm = wred_max(lv);
      float vv = expf(lv - vm);
      float q0 = 0.f, q1r = 0.f, q2 = 0.f, q3 = 0.f;
#pragma unroll
      for (int j = 0; j < 16; j++){
        q0  = fmaf(PTreg[j],      __shfl(vv, j,      64), q0);
        q1r = fmaf(PTreg[j + 16], __shfl(vv, j + 16, 64), q1r);
        q2  = fmaf(PTreg[j + 32], __shfl(vv, j + 32, 64), q2);
        q3  = fmaf(PTreg[j + 48], __shfl(vv, j + 48, 64), q3);
      }
      float bn = (q0 + q1r) + (q2 + q3);
      float bmax = wred_max(bn);
      b = bn / bmax;
      lb = logf(b);
      betahat[(size_t)t*KK + lane] = b;
      lgb = lgbn; mrn = mrnn;
    }
  }
}

// ---------------- merged outputs: rhat + xihat + ll ----------------
__global__ void __launch_bounds__(256) k_outs(const float* __restrict__ ah,
     const float* __restrict__ bh, const float* __restrict__ ElogA,
     const float* __restrict__ logB, const float* __restrict__ llp,
     float* __restrict__ out_rhat, float* __restrict__ out_xi, float* __restrict__ out_ll)
{
  __shared__ float la[64], wc[64];
  __shared__ float redm[4], reds[4];
  int tid = threadIdx.x;
  int b = blockIdx.x;
  if (tid < 64) la[tid] = logf(ah[(size_t)b*KK + tid]);
  else if (tid < 128 && b < T_LEN-1){
    int j = tid - 64;
    wc[j] = logB[(size_t)(b+1)*KK + j] + logf(bh[(size_t)(b+1)*KK + j]);
  }
  __syncthreads();
  // rhat row b (wave 0)
  if (tid < 64){
    float s = la[tid] + logf(bh[(size_t)b*KK + tid]);
    float m = wred_max(s);
    float p = (m < -3.0e37f) ? 1.f : expf(s - m);
    float ss = wred_sum(p);
    out_rhat[(size_t)b*KK + tid] = p/ss;
  }
  if (b == T_LEN-1){
    if (tid >= 64 && tid < 128){
      int i = tid - 64;
      float v = llp[i] + llp[i + 64];
      v = wred_sum(v);
      if (i == 0) out_ll[0] = v;
    }
    return;
  }
  // xihat row t=b+1
  int r = tid >> 6, j = tid & 63;
  float sv[16];
  float mx = -3.0e38f;
#pragma unroll
  for (int n = 0; n < 16; n++){
    int i = r + n*4;
    float s = la[i] + ElogA[i*KK + j] + wc[j];
    sv[n] = s;
    mx = fmaxf(mx, s);
  }
  float mxw = wred_max(mx);
  if ((tid & 63) == 0) redm[tid >> 6] = mxw;
  __syncthreads();
  float m = fmaxf(fmaxf(redm[0], redm[1]), fmaxf(redm[2], redm[3]));
  bool degen = !(m > -3.0e37f);
  float pv[16]; float ps = 0.f;
#pragma unroll
  for (int n = 0; n < 16; n++){
    float p = degen ? 1.f : expf(sv[n] - m);
    pv[n] = p; ps += p;
  }
  float psw = wred_sum(ps);
  if ((tid & 63) == 0) reds[tid >> 6] = psw;
  __syncthreads();
  float inv = 1.f/(reds[0] + reds[1] + reds[2] + reds[3]);
  float* dst = out_xi + (size_t)b*4096;
#pragma unroll
  for (int n = 0; n < 16; n++){
    int i = r + n*4;
    dst[i*KK + j] = pv[n]*inv;
  }
}

extern "C" void kernel_launch(void* const* d_in, const int* in_sizes, int n_in,
                              void* d_out, int out_size, void* d_ws, size_t ws_size,
                              hipStream_t stream)
{
  const float* mu    = (const float*)d_in[0];
  const float* dvar  = (const float*)d_in[1];
  const float* niwmu = (const float*)d_in[2];
  const float* Psi   = (const float*)d_in[3];
  const float* nu    = (const float*)d_in[4];
  const float* phi   = (const float*)d_in[5];
  const float* lpi   = (const float*)d_in[6];
  float* out = (float*)d_out;
  float* ws  = (float*)d_ws;

  size_t o = 0;
  float* EbfF   = ws + o; o += (size_t)DD*DD*KK/2;
  float* EdiagT = ws + o; o += (size_t)DD*KK;
  float* cvecT  = ws + o; o += (size_t)DD*KK;
  float* rK     = ws + o; o += KK;
  float* Lhalf  = ws + o; o += KK;
  float* sclK   = ws + o; o += KK;
  float* ElogA  = ws + o; o += KK*KK;
  float* P      = ws + o; o += KK*KK;
  float* PT     = ws + o; o += KK*KK;
  float* logB   = ws + o; o += (size_t)T_LEN*KK;
  float* mrowp  = ws + o; o += T_LEN;
  float* btil   = ws + o; o += (size_t)T_LEN*KK;
  float* G8     = ws + o; o += (size_t)1024*4096;
  float* H64    = ws + o; o += (size_t)128*4096;
  float* LH64   = ws + o; o += (size_t)128*4096;
  float* H128   = ws + o; o += (size_t)64*4096;
  float* LH128  = ws + o; o += (size_t)64*4096;
  float* aB     = ws + o; o += 64*64;
  float* bB     = ws + o; o += 64*64;
  float* llp    = ws + o; o += 128;
  float* ah     = ws + o; o += (size_t)T_LEN*KK;
  float* bh     = ws + o; o += (size_t)T_LEN*KK;
  if (ws_size < o*sizeof(float)) return;

  __bf16* Ebf = (__bf16*)EbfF;
  float*  part = G8;   // alias: consumed by k_logBall before k_pass1 writes G8

  hipFuncSetAttribute((const void*)k_neumann, hipFuncAttributeMaxDynamicSharedMemorySize, 2*DD*RS*4);
  hipFuncSetAttribute((const void*)k_logBall, hipFuncAttributeMaxDynamicSharedMemorySize, 2*DD*KK*4);

  k_neumann<<<64, 256, 2*DD*RS*4, stream>>>(Psi, niwmu, nu, phi, Ebf, EdiagT, cvecT, rK, Lhalf, sclK, ElogA, P, PT);
  k_q1<<<512, 256, 0, stream>>>(mu, Ebf, part);
  k_logBall<<<256, 256, 2*DD*KK*4, stream>>>(part, mu, dvar, cvecT, EdiagT, rK, Lhalf, sclK, logB, mrowp, btil);
  k_pass1<<<1024, 128, 0, stream>>>(P, btil, G8);
  k_chain<<<128, 256, 0, stream>>>(G8, H64, LH64, 8);
  k_chain<<<64, 256, 0, stream>>>(H64, H128, LH128, 2);
  k_pass2<<<2, 256, 0, stream>>>(H128, logB, lpi, aB, bB);
  k_pass3<<<256, 64, 0, stream>>>(P, PT, LH64, logB, mrowp, btil, lpi, aB, bB, ah, bh, llp);
  k_outs<<<T_LEN, 256, 0, stream>>>(ah, bh, ElogA, logB, llp, out, out + (size_t)T_LEN*KK,
                                    out + (size_t)T_LEN*KK + (size_t)(T_LEN-1)*KK*KK);
}

// Round 5
// 458.402 us; speedup vs baseline: 3.4446x; 1.0944x over previous
//
#include <hip/hip_runtime.h>
#include <math.h>

#define T_LEN 8192
#define KK 64
#define DD 128
#define RS 132
#define MUPB 136
#define GP 68

typedef __bf16  bf16x4 __attribute__((ext_vector_type(4)));
typedef __bf16  bf16x8 __attribute__((ext_vector_type(8)));
typedef float  f32x16 __attribute__((ext_vector_type(16)));

__device__ __forceinline__ float wred_max(float v){
#pragma unroll
  for (int m = 1; m < 64; m <<= 1) v = fmaxf(v, __shfl_xor(v, m, 64));
  return v;
}
__device__ __forceinline__ float wred_sum(float v){
#pragma unroll
  for (int m = 1; m < 64; m <<= 1) v += __shfl_xor(v, m, 64);
  return v;
}
__device__ __forceinline__ float digamma_f(float x){
  float r = 0.f;
  while (x < 6.f){ r -= 1.f/x; x += 1.f; }
  float ix = 1.f/x, ix2 = ix*ix;
  return r + logf(x) - 0.5f*ix - ix2*(0.0833333333f - ix2*(0.0083333333f - ix2*0.0039682540f));
}

// ---------------- Neumann inverse + logdet + ElogA/P/PT ----------------
__global__ void __launch_bounds__(256, 1) k_neumann(
    const float* __restrict__ Psi, const float* __restrict__ niw_mu,
    const float* __restrict__ nu_, const float* __restrict__ phi,
    __bf16* __restrict__ Ebf, float* __restrict__ EdiagT,
    float* __restrict__ cvecT, float* __restrict__ rK, float* __restrict__ Lhalf,
    float* __restrict__ sclK,
    float* __restrict__ ElogA, float* __restrict__ P, float* __restrict__ PT)
{
  extern __shared__ float lds[];
  float* Rl = lds;            // [DD][RS]
  float* Pb = lds + DD*RS;    // [DD][RS]
  __shared__ float red[256];
  __shared__ float msh[DD];
  int k = blockIdx.x, tid = threadIdx.x;
  const float* A = Psi + (size_t)k*DD*DD;

  if (tid < 64){
    float ph = phi[k*KK + tid];
    float s  = wred_sum(ph);
    float e  = digamma_f(ph) - digamma_f(s);
    ElogA[k*KK + tid] = e;
    float p = expf(e);
    P [k*KK + tid] = p;
    PT[tid*KK + k] = p;
  }

  float tl = 0.f;
  for (int d = tid; d < DD; d += 256) tl += A[d*DD + d];
  red[tid] = tl; __syncthreads();
  for (int off = 128; off > 0; off >>= 1){ if (tid < off) red[tid] += red[tid+off]; __syncthreads(); }
  float c = red[0] / (float)DD;
  __syncthreads();

  float trpow = 0.f;
  for (int idx = tid; idx < DD*DD; idx += 256){
    int d = idx >> 7, e = idx & 127;
    float v = ((d == e) ? 1.f : 0.f) - A[idx]/c;
    Rl[d*RS + e] = v;
    if (d == e) trpow += v;
  }
  __syncthreads();

  int tr = tid >> 4, tc = tid & 15;
  int r0 = tr*8, c0 = tc*8;
  float S[8][8];
#pragma unroll
  for (int i = 0; i < 8; i++)
#pragma unroll
    for (int j = 0; j < 8; j++){
      float v = Rl[(r0+i)*RS + c0+j];
      if (r0+i == c0+j) v += 1.f;
      S[i][j] = v;
    }

  {
    float Cc[8][8];
#pragma unroll
    for (int i = 0; i < 8; i++)
#pragma unroll
      for (int j = 0; j < 8; j++) Cc[i][j] = 0.f;
    for (int l = 0; l < DD; l += 4){
      float af[4][8], bf[4][8];
#pragma unroll
      for (int q = 0; q < 4; q++){
        float4 x0 = *(const float4*)&Rl[(l+q)*RS + r0];
        float4 x1 = *(const float4*)&Rl[(l+q)*RS + r0 + 4];
        af[q][0]=x0.x; af[q][1]=x0.y; af[q][2]=x0.z; af[q][3]=x0.w;
        af[q][4]=x1.x; af[q][5]=x1.y; af[q][6]=x1.z; af[q][7]=x1.w;
        float4 y0 = *(const float4*)&Rl[(l+q)*RS + c0];
        float4 y1 = *(const float4*)&Rl[(l+q)*RS + c0 + 4];
        bf[q][0]=y0.x; bf[q][1]=y0.y; bf[q][2]=y0.z; bf[q][3]=y0.w;
        bf[q][4]=y1.x; bf[q][5]=y1.y; bf[q][6]=y1.z; bf[q][7]=y1.w;
      }
#pragma unroll
      for (int q = 0; q < 4; q++)
#pragma unroll
        for (int i = 0; i < 8; i++)
#pragma unroll
          for (int j = 0; j < 8; j++)
            Cc[i][j] = fmaf(af[q][i], bf[q][j], Cc[i][j]);
    }
#pragma unroll
    for (int i = 0; i < 8; i++)
#pragma unroll
      for (int j = 0; j < 8; j++) S[i][j] += Cc[i][j];
    if (tr == tc){
#pragma unroll
      for (int i = 0; i < 8; i++) trpow += Cc[i][i]*0.5f;
    }
  }

  red[tid] = trpow; __syncthreads();
  for (int off = 128; off > 0; off >>= 1){ if (tid < off) red[tid] += red[tid+off]; __syncthreads(); }
  float trsum = red[0];
  __syncthreads();

  float nu = nu_[k];
  float dl = 0.f;
  for (int i = tid; i < DD; i += 256) dl += digamma_f((nu - (float)i)*0.5f);
  red[tid] = dl; __syncthreads();
  for (int off = 128; off > 0; off >>= 1){ if (tid < off) red[tid] += red[tid+off]; __syncthreads(); }
  if (tid == 0){
    float logdetPsi = (float)DD*logf(c) - trsum;
    float Elogdet = red[0] + (float)DD*0.69314718056f - logdetPsi;
    Lhalf[k] = 0.5f*Elogdet - 0.5f*(float)DD*1.83787706641f;
    sclK[k]  = nu / c;
  }
  __syncthreads();

  float scl = nu / c;
#pragma unroll
  for (int i = 0; i < 8; i++)
#pragma unroll
    for (int j = 0; j < 8; j++){
      float sv = S[i][j];
      bool dg = (r0+i == c0+j);
      if (dg) EdiagT[(r0+i)*KK + k] = scl*sv;
      float et = scl*(sv - (dg ? 1.f : 0.f));
      int r = (r0+i)*DD + (c0+j);
      Ebf[(size_t)(r>>4)*1024 + k*16 + (r&15)] = (__bf16)et;
    }
#pragma unroll
  for (int i = 0; i < 8; i++){
    float4 w0, w1;
    w0.x=S[i][0]; w0.y=S[i][1]; w0.z=S[i][2]; w0.w=S[i][3];
    w1.x=S[i][4]; w1.y=S[i][5]; w1.z=S[i][6]; w1.w=S[i][7];
    *(float4*)&Pb[(r0+i)*RS + c0]     = w0;
    *(float4*)&Pb[(r0+i)*RS + c0 + 4] = w1;
  }
  for (int d = tid; d < DD; d += 256) msh[d] = niw_mu[k*DD + d];
  __syncthreads();
  float cv = 0.f;
  if (tid < DD){
    float acc = 0.f;
    for (int e = 0; e < DD; e++) acc += Pb[tid*RS + e]*msh[e];
    cv = scl*acc;
    cvecT[tid*KK + k] = cv;
  }
  red[tid] = (tid < DD) ? msh[tid]*cv : 0.f; __syncthreads();
  for (int off = 128; off > 0; off >>= 1){ if (tid < off) red[tid] += red[tid+off]; __syncthreads(); }
  if (tid == 0) rK[k] = red[0];
}

// ---------------- residual quad GEMM ----------------
__global__ void __launch_bounds__(256) k_q1(const float* __restrict__ mu,
      const __bf16* __restrict__ Ebf, float* __restrict__ part)
{
  __shared__ __bf16 muL[64*MUPB];
  __shared__ __bf16 Bp[2][4][64*24];
  int b = blockIdx.x;
  int rs = b & 3, tseg = b >> 2;
  int t0 = tseg*64, d0 = rs*32;
  int tid = threadIdx.x;
  int w = tid >> 6, lane = tid & 63;
  int tl = (w>>1)*32 + (lane&31);
  int nc = (w&1)*32 + (lane&31);
  int k0 = (lane>>5)*8;

  for (int v = tid; v < 64*32; v += 256){
    int t = v >> 5, seg = v & 31;
    float4 x = *(const float4*)&mu[(size_t)(t0+t)*DD + seg*4];
    bf16x4 hv;
    hv[0] = (__bf16)x.x; hv[1] = (__bf16)x.y; hv[2] = (__bf16)x.z; hv[3] = (__bf16)x.w;
    *(bf16x4*)&muL[t*MUPB + seg*4] = hv;
  }
  {
    const unsigned long long* gp = (const unsigned long long*)(Ebf + (size_t)(d0*8)*1024);
#pragma unroll
    for (int q = 0; q < 4; q++){
      unsigned long long v = gp[q*256 + tid];
      *((unsigned long long*)&Bp[0][q][(tid>>2)*24 + (tid&3)*4]) = v;
    }
  }
  __syncthreads();

  f32x16 acc;
#pragma unroll
  for (int i = 0; i < 16; i++) acc[i] = 0.f;

  for (int ss = 0; ss < 64; ss++){
    unsigned long long pre[4];
    bool more = (ss < 63);
    if (more){
      const unsigned long long* gp = (const unsigned long long*)(Ebf + (size_t)(d0*8 + (ss+1)*4)*1024);
#pragma unroll
      for (int q = 0; q < 4; q++) pre[q] = gp[q*256 + tid];
    }
#pragma unroll
    for (int q = 0; q < 4; q++){
      int s = ss*4 + q;
      int d = d0 + (s>>3), e0 = (s&7)<<4;
      float mud = (float)muL[tl*MUPB + d];
      bf16x8 mv = *(const bf16x8*)&muL[tl*MUPB + e0 + k0];
      bf16x8 af;
#pragma unroll
      for (int j = 0; j < 8; j++) af[j] = (__bf16)(mud * (float)mv[j]);
      bf16x8 bfr = *(const bf16x8*)&Bp[ss&1][q][nc*24 + k0];
      acc = __builtin_amdgcn_mfma_f32_32x32x16_bf16(af, bfr, acc, 0, 0, 0);
    }
    if (more){
#pragma unroll
      for (int q = 0; q < 4; q++)
        *((unsigned long long*)&Bp[(ss+1)&1][q][(tid>>2)*24 + (tid&3)*4]) = pre[q];
    }
    __syncthreads();
  }

  float* dst = part + (size_t)rs*T_LEN*KK;
#pragma unroll
  for (int r = 0; r < 16; r++){
    int row = (r&3) + 8*(r>>2) + 4*(lane>>5);
    int t = t0 + (w>>1)*32 + row;
    dst[(size_t)t*KK + nc] = acc[r];
  }
}

// ---------------- finalize logB: d-outer/t-inner, registers hoisted ----------------
__global__ void __launch_bounds__(256) k_logBall(
    const float* __restrict__ part, const float* __restrict__ mu, const float* __restrict__ dvar,
    const float* __restrict__ cvecT, const float* __restrict__ EdiagT,
    const float* __restrict__ rK, const float* __restrict__ Lhalf, const float* __restrict__ sclK,
    float* __restrict__ logB, float* __restrict__ mrow, float* __restrict__ btil)
{
  extern __shared__ float lds[];
  float* cv = lds; float* ed = lds + DD*KK;
  int tid = threadIdx.x; int k = tid & 63; int w = tid >> 6;
  for (int v = tid; v < DD*KK; v += 256){ cv[v] = cvecT[v]; ed[v] = EdiagT[v]; }
  __syncthreads();
  float rk = rK[k], lh = Lhalf[k], scl = sclK[k];
  int tbase = blockIdx.x*32 + w*8;
  float a1[8], a2[8], ssv[8];
#pragma unroll
  for (int tt = 0; tt < 8; tt++){ a1[tt]=0.f; a2[tt]=0.f; ssv[tt]=0.f; }
  for (int dc = 0; dc < DD; dc += 4){
    float c0 = cv[(dc+0)*KK + k], c1 = cv[(dc+1)*KK + k];
    float c2 = cv[(dc+2)*KK + k], c3 = cv[(dc+3)*KK + k];
    float e0 = ed[(dc+0)*KK + k], e1 = ed[(dc+1)*KK + k];
    float e2 = ed[(dc+2)*KK + k], e3 = ed[(dc+3)*KK + k];
#pragma unroll
    for (int tt = 0; tt < 8; tt++){
      float4 m4 = *(const float4*)(mu   + (size_t)(tbase+tt)*DD + dc);
      float4 v4 = *(const float4*)(dvar + (size_t)(tbase+tt)*DD + dc);
      a1[tt] = fmaf(m4.x,c0, fmaf(m4.y,c1, fmaf(m4.z,c2, fmaf(m4.w,c3, a1[tt]))));
      a2[tt] = fmaf(fmaxf(v4.x,0.f),e0, fmaf(fmaxf(v4.y,0.f),e1,
               fmaf(fmaxf(v4.z,0.f),e2, fmaf(fmaxf(v4.w,0.f),e3, a2[tt]))));
      ssv[tt] = fmaf(m4.x,m4.x, fmaf(m4.y,m4.y, fmaf(m4.z,m4.z, fmaf(m4.w,m4.w, ssv[tt]))));
    }
  }
#pragma unroll
  for (int tt = 0; tt < 8; tt++){
    int t = tbase + tt;
    float q = scl*ssv[tt]
            + part[(size_t)0*T_LEN*KK + (size_t)t*KK + k]
            + part[(size_t)1*T_LEN*KK + (size_t)t*KK + k]
            + part[(size_t)2*T_LEN*KK + (size_t)t*KK + k]
            + part[(size_t)3*T_LEN*KK + (size_t)t*KK + k];
    float lb = lh - 0.5f*(q - 2.f*a1[tt] + rk + a2[tt]);
    float m  = wred_max(lb);
    logB[(size_t)t*KK + k] = lb;
    btil[(size_t)t*KK + k] = expf(lb - m);
    if (k == 0) mrow[t] = m;
  }
}

// ---------------- pass1: 8-step chunk operators via bf16 hi/lo MFMA ----------------
__global__ void __launch_bounds__(128, 1) k_pass1(const float* __restrict__ Pm,
     const float* __restrict__ btil, float* __restrict__ G8)
{
  __shared__ float G[64*GP];
  __shared__ float wmax[2][2];
  int tid = threadIdx.x, w = tid >> 6, lane = tid & 63;
  int chunk = blockIdx.x;
  int kb8 = (lane >> 5)*8;
  int n = lane & 31;

  bf16x8 Bhi[4][2], Blo[4][2];
#pragma unroll
  for (int Kb = 0; Kb < 4; Kb++)
#pragma unroll
    for (int J = 0; J < 2; J++){
#pragma unroll
      for (int j = 0; j < 8; j++){
        float p = Pm[(Kb*16 + kb8 + j)*KK + J*32 + n];
        __bf16 h = (__bf16)p;
        Bhi[Kb][J][j] = h;
        Blo[Kb][J][j] = (__bf16)(p - (float)h);
      }
    }
  for (int v = tid; v < 64*64; v += 128){
    int i = v >> 6, j = v & 63;
    G[i*GP + j] = (i == j) ? 1.f : 0.f;
  }
  __syncthreads();

  int m = w*32 + n;
  for (int s = 0; s < 8; s++){
    int t = chunk*8 + s;
    if (t >= 1){
      f32x16 acc0, acc1;
#pragma unroll
      for (int i = 0; i < 16; i++){ acc0[i] = 0.f; acc1[i] = 0.f; }
#pragma unroll
      for (int Kb = 0; Kb < 4; Kb++){
        float4 x0 = *(const float4*)&G[m*GP + Kb*16 + kb8];
        float4 x1 = *(const float4*)&G[m*GP + Kb*16 + kb8 + 4];
        float xv[8] = {x0.x,x0.y,x0.z,x0.w,x1.x,x1.y,x1.z,x1.w};
        bf16x8 ah, al;
#pragma unroll
        for (int j = 0; j < 8; j++){
          __bf16 h = (__bf16)xv[j];
          ah[j] = h;
          al[j] = (__bf16)(xv[j] - (float)h);
        }
        acc0 = __builtin_amdgcn_mfma_f32_32x32x16_bf16(ah, Bhi[Kb][0], acc0, 0,0,0);
        acc0 = __builtin_amdgcn_mfma_f32_32x32x16_bf16(ah, Blo[Kb][0], acc0, 0,0,0);
        acc0 = __builtin_amdgcn_mfma_f32_32x32x16_bf16(al, Bhi[Kb][0], acc0, 0,0,0);
        acc1 = __builtin_amdgcn_mfma_f32_32x32x16_bf16(ah, Bhi[Kb][1], acc1, 0,0,0);
        acc1 = __builtin_amdgcn_mfma_f32_32x32x16_bf16(ah, Blo[Kb][1], acc1, 0,0,0);
        acc1 = __builtin_amdgcn_mfma_f32_32x32x16_bf16(al, Bhi[Kb][1], acc1, 0,0,0);
      }
      float b0 = btil[(size_t)t*KK + n];
      float b1 = btil[(size_t)t*KK + 32 + n];
      float mx = 0.f;
#pragma unroll
      for (int i = 0; i < 16; i++){
        acc0[i] *= b0; acc1[i] *= b1;
        mx = fmaxf(mx, fmaxf(acc0[i], acc1[i]));
      }
      mx = wred_max(mx);
      if (lane == 0) wmax[s&1][w] = mx;
      __syncthreads();
      float inv = 1.f/fmaxf(wmax[s&1][0], wmax[s&1][1]);
#pragma unroll
      for (int r = 0; r < 16; r++){
        int row = w*32 + (r&3) + 8*(r>>2) + 4*(lane>>5);
        G[row*GP + n]      = acc0[r]*inv;
        G[row*GP + 32 + n] = acc1[r]*inv;
      }
    }
  }
  __syncthreads();
  float* dst = G8 + (size_t)chunk*4096;
  for (int v = tid; v < 4096; v += 128) dst[v] = G[(v>>6)*GP + (v&63)];
}

// ---------------- chain-combine via bf16 hi/lo MFMA ----------------
__global__ void __launch_bounds__(128, 1) k_chainM(const float* __restrict__ src,
        float* __restrict__ dstLin, float* __restrict__ dstLog, float* __restrict__ dstT,
        int chain)
{
  __shared__ float X[64*GP];
  __shared__ float wmax[2][2];
  int tid = threadIdx.x, w = tid >> 6, lane = tid & 63;
  int cb = blockIdx.x;
  int kb8 = (lane >> 5)*8;
  int n = lane & 31;
  const float* s0 = src + (size_t)cb*chain*4096;

  for (int v = tid; v < 4096; v += 128) X[(v>>6)*GP + (v&63)] = s0[v];
  __syncthreads();

  int m = w*32 + n;
  for (int j = 1; j < chain; j++){
    const float* Y = s0 + (size_t)j*4096;
    bf16x8 Bh[4][2], Bl[4][2];
#pragma unroll
    for (int Kb = 0; Kb < 4; Kb++)
#pragma unroll
      for (int J = 0; J < 2; J++){
#pragma unroll
        for (int jj = 0; jj < 8; jj++){
          float p = Y[(Kb*16 + kb8 + jj)*64 + J*32 + n];
          __bf16 h = (__bf16)p;
          Bh[Kb][J][jj] = h;
          Bl[Kb][J][jj] = (__bf16)(p - (float)h);
        }
      }
    f32x16 acc0, acc1;
#pragma unroll
    for (int i = 0; i < 16; i++){ acc0[i] = 0.f; acc1[i] = 0.f; }
#pragma unroll
    for (int Kb = 0; Kb < 4; Kb++){
      float4 x0 = *(const float4*)&X[m*GP + Kb*16 + kb8];
      float4 x1 = *(const float4*)&X[m*GP + Kb*16 + kb8 + 4];
      float xv[8] = {x0.x,x0.y,x0.z,x0.w,x1.x,x1.y,x1.z,x1.w};
      bf16x8 ah, al;
#pragma unroll
      for (int q = 0; q < 8; q++){
        __bf16 h = (__bf16)xv[q];
        ah[q] = h;
        al[q] = (__bf16)(xv[q] - (float)h);
      }
      acc0 = __builtin_amdgcn_mfma_f32_32x32x16_bf16(ah, Bh[Kb][0], acc0, 0,0,0);
      acc0 = __builtin_amdgcn_mfma_f32_32x32x16_bf16(ah, Bl[Kb][0], acc0, 0,0,0);
      acc0 = __builtin_amdgcn_mfma_f32_32x32x16_bf16(al, Bh[Kb][0], acc0, 0,0,0);
      acc1 = __builtin_amdgcn_mfma_f32_32x32x16_bf16(ah, Bh[Kb][1], acc1, 0,0,0);
      acc1 = __builtin_amdgcn_mfma_f32_32x32x16_bf16(ah, Bl[Kb][1], acc1, 0,0,0);
      acc1 = __builtin_amdgcn_mfma_f32_32x32x16_bf16(al, Bh[Kb][1], acc1, 0,0,0);
    }
    float mx = 0.f;
#pragma unroll
    for (int i = 0; i < 16; i++) mx = fmaxf(mx, fmaxf(acc0[i], acc1[i]));
    mx = wred_max(mx);
    if (lane == 0) wmax[j&1][w] = mx;
    __syncthreads();
    float inv = 1.f/fmaxf(wmax[j&1][0], wmax[j&1][1]);
#pragma unroll
    for (int r = 0; r < 16; r++){
      int row = w*32 + (r&3) + 8*(r>>2) + 4*(lane>>5);
      X[row*GP + n]      = acc0[r]*inv;
      X[row*GP + 32 + n] = acc1[r]*inv;
    }
  }
  __syncthreads();
  for (int v = tid; v < 4096; v += 128){
    float vv = X[(v>>6)*GP + (v&63)];
    dstLin[(size_t)cb*4096 + v] = vv;
    if (dstLog) dstLog[(size_t)cb*4096 + v] = logf(vv);
  }
  if (dstT){
    for (int v = tid; v < 4096; v += 128)
      dstT[(size_t)cb*4096 + v] = X[(v&63)*GP + (v>>6)];
  }
}

// ---------------- pass2: register-resident sequential matvec scan ----------------
#define P2_LOAD(H, base, cc) do { const float* g_ = (base) + (size_t)(cc)*4096; \
  _Pragma("unroll") for (int i_ = 0; i_ < 64; i_++) H[i_] = g_[i_*64 + lane]; } while(0)
#define P2_STEP_SUM(H, v) do { float p0_=0.f,p1_=0.f,p2_=0.f,p3_=0.f; \
  _Pragma("unroll") for (int i_ = 0; i_ < 16; i_++){ \
    p0_ = fmaf(__shfl(v, i_,      64), H[i_],      p0_); \
    p1_ = fmaf(__shfl(v, i_ + 16, 64), H[i_ + 16], p1_); \
    p2_ = fmaf(__shfl(v, i_ + 32, 64), H[i_ + 32], p2_); \
    p3_ = fmaf(__shfl(v, i_ + 48, 64), H[i_ + 48], p3_); } \
  float p_ = (p0_ + p1_) + (p2_ + p3_); \
  v = p_ / wred_sum(p_); } while(0)
#define P2_STEP_MAX(H, v) do { float p0_=0.f,p1_=0.f,p2_=0.f,p3_=0.f; \
  _Pragma("unroll") for (int i_ = 0; i_ < 16; i_++){ \
    p0_ = fmaf(__shfl(v, i_,      64), H[i_],      p0_); \
    p1_ = fmaf(__shfl(v, i_ + 16, 64), H[i_ + 16], p1_); \
    p2_ = fmaf(__shfl(v, i_ + 32, 64), H[i_ + 32], p2_); \
    p3_ = fmaf(__shfl(v, i_ + 48, 64), H[i_ + 48], p3_); } \
  float p_ = (p0_ + p1_) + (p2_ + p3_); \
  v = p_ / wred_max(p_); } while(0)

__global__ void __launch_bounds__(64, 1) k_pass2(const float* __restrict__ H128,
    const float* __restrict__ HT128,
    const float* __restrict__ logB, const float* __restrict__ log_pi,
    float* __restrict__ aB, float* __restrict__ bB)
{
  int lane = threadIdx.x;
  float Ha[64], Hb2[64];
  if (blockIdx.x == 0){
    float v;
    {
      float x = log_pi[lane] + logB[lane];
      float mm = wred_max(x);
      float e = expf(x - mm);
      v = e / wred_sum(e);
    }
    P2_LOAD(Ha, H128, 0);
    for (int c = 0; c < 64; c += 2){
      if (c + 1 < 64) P2_LOAD(Hb2, H128, c + 1);
      P2_STEP_SUM(Ha, v);
      aB[c*64 + lane] = v;
      if (c + 1 < 64){
        if (c + 2 < 64) P2_LOAD(Ha, H128, c + 2);
        P2_STEP_SUM(Hb2, v);
        aB[(c+1)*64 + lane] = v;
      }
    }
  } else {
    float b = 1.f;
    bB[63*64 + lane] = 1.f;
    P2_LOAD(Ha, HT128, 63);
    for (int c = 63; c >= 1; c -= 2){
      if (c - 1 >= 1) P2_LOAD(Hb2, HT128, c - 1);
      P2_STEP_MAX(Ha, b);
      bB[(c-1)*64 + lane] = b;
      if (c - 1 >= 1){
        if (c - 2 >= 1) P2_LOAD(Ha, HT128, c - 2);
        P2_STEP_MAX(Hb2, b);
        bB[(c-2)*64 + lane] = b;
      }
    }
  }
}

// ---------------- pass3: per-64-step-chunk exact recurrences ----------------
__global__ void __launch_bounds__(64, 1) k_pass3(const float* __restrict__ Pm, const float* __restrict__ PTm,
   const float* __restrict__ LH64,
   const float* __restrict__ logB, const float* __restrict__ mrow, const float* __restrict__ btil,
   const float* __restrict__ log_pi,
   const float* __restrict__ aB, const float* __restrict__ bB,
   float* __restrict__ alphahat, float* __restrict__ betahat, float* __restrict__ llpart)
{
  __shared__ float Hl[64*68];
  __shared__ float vl[64];
  int lane = threadIdx.x;
  int bid = blockIdx.x;
  if (bid < 128){
    int c = bid;
    float Preg[64];
#pragma unroll
    for (int i = 0; i < 64; i++) Preg[i] = Pm[i*64 + lane];
    float a; float llacc = 0.f;
    int tstart;
    if (c == 0){
      float v = log_pi[lane] + logB[lane];
      float m = wred_max(v);
      float e = expf(v - m);
      float s = wred_sum(e);
      a = e/s;
      llacc = m + logf(s);
      alphahat[lane] = a;
      tstart = 1;
    } else if (c & 1){
      float lp;
      if (c == 1){
        float v = log_pi[lane] + logB[lane];
        float m = wred_max(v);
        lp = v - m;
      } else {
        lp = logf(aB[((c-1)/2 - 1)*64 + lane]);
      }
      for (int u = lane; u < 1024; u += 64){
        float4 x = ((const float4*)(LH64 + (size_t)(c-1)*4096))[u];
        int row = u >> 4, col = (u & 15)*4;
        *(float4*)&Hl[row*68 + col] = x;
      }
      vl[lane] = lp;
      __syncthreads();
      float mx = -3.0e38f;
      for (int i = 0; i < 64; i++) mx = fmaxf(mx, vl[i] + Hl[i*68 + lane]);
      float s = 0.f;
      for (int i = 0; i < 64; i++) s += expf(vl[i] + Hl[i*68 + lane] - mx);
      float ln = mx + logf(s);
      float mm = wred_max(ln);
      float e  = expf(ln - mm);
      float ss = wred_sum(e);
      a = e/ss;
      __syncthreads();
      tstart = c*64;
    } else {
      a = aB[(c/2 - 1)*64 + lane];
      tstart = c*64;
    }
    int tend = c*64 + 64;
    float bt = btil[(size_t)tstart*KK + lane];
    for (int t = tstart; t < tend; t++){
      float btn = 0.f;
      if (t + 1 < tend) btn = btil[(size_t)(t+1)*KK + lane];
      float mr = mrow[t];
      float p0 = 0.f, p1 = 0.f, p2 = 0.f, p3 = 0.f;
#pragma unroll
      for (int i = 0; i < 16; i++){
        p0 = fmaf(__shfl(a, i,      64), Preg[i],      p0);
        p1 = fmaf(__shfl(a, i + 16, 64), Preg[i + 16], p1);
        p2 = fmaf(__shfl(a, i + 32, 64), Preg[i + 32], p2);
        p3 = fmaf(__shfl(a, i + 48, 64), Preg[i + 48], p3);
      }
      float pred = (p0 + p1) + (p2 + p3);
      float at = pred * bt;
      float s  = wred_sum(at);
      a = at / s;
      llacc += logf(s) + mr;
      alphahat[(size_t)t*KK + lane] = a;
      bt = btn;
    }
    if (lane == 0) llpart[c] = llacc;
  } else {
    int c = bid - 128;
    float PTreg[64];
#pragma unroll
    for (int j = 0; j < 64; j++) PTreg[j] = PTm[j*64 + lane];
    float b, lb;
    if (c == 127){
      b = 1.f; lb = 0.f;
    } else if (c & 1){
      b = bB[((c-1)/2)*64 + lane];
      lb = logf(b);
    } else {
      float lbin = logf(bB[(c/2)*64 + lane]);
      for (int u = lane; u < 1024; u += 64){
        float4 x = ((const float4*)(LH64 + (size_t)(c+1)*4096))[u];
        int row = u >> 4, col = (u & 15)*4;
        Hl[(col+0)*68 + row] = x.x; Hl[(col+1)*68 + row] = x.y;
        Hl[(col+2)*68 + row] = x.z; Hl[(col+3)*68 + row] = x.w;
      }
      vl[lane] = lbin;
      __syncthreads();
      float mx = -3.0e38f;
      for (int j = 0; j < 64; j++) mx = fmaxf(mx, Hl[j*68 + lane] + vl[j]);
      float s = 0.f;
      for (int j = 0; j < 64; j++) s += expf(Hl[j*68 + lane] + vl[j] - mx);
      float ln = mx + logf(s);
      float mm = wred_max(ln);
      lb = ln - mm;
      b = expf(lb);
      __syncthreads();
    }
    int t1 = c*64 + 63;
    betahat[(size_t)t1*KK + lane] = b;
    float lgb = logB[(size_t)t1*KK + lane];
    float mrn = mrow[t1];
    for (int t = t1 - 1; t >= c*64; t--){
      float lgbn = 0.f, mrnn = 0.f;
      if (t > c*64){
        lgbn = logB[(size_t)t*KK + lane];
        mrnn = mrow[t];
      }
      float lv = (lgb - mrn) + lb;
      float vm = wred_max(lv);
      float vv = expf(lv - vm);
      float q0 = 0.f, q1r = 0.f, q2 = 0.f, q3 = 0.f;
#pragma unroll
      for (int j = 0; j < 16; j++){
        q0  = fmaf(PTreg[j],      __shfl(vv, j,      64), q0);
        q1r = fmaf(PTreg[j + 16], __shfl(vv, j + 16, 64), q1r);
        q2  = fmaf(PTreg[j + 32], __shfl(vv, j + 32, 64), q2);
        q3  = fmaf(PTreg[j + 48], __shfl(vv, j + 48, 64), q3);
      }
      float bn = (q0 + q1r) + (q2 + q3);
      float bmax = wred_max(bn);
      b = bn / bmax;
      lb = logf(b);
      betahat[(size_t)t*KK + lane] = b;
      lgb = lgbn; mrn = mrnn;
    }
  }
}

// ---------------- merged outputs: rhat + xihat + ll ----------------
__global__ void __launch_bounds__(256) k_outs(const float* __restrict__ ah,
     const float* __restrict__ bh, const float* __restrict__ ElogA,
     const float* __restrict__ logB, const float* __restrict__ llp,
     float* __restrict__ out_rhat, float* __restrict__ out_xi, float* __restrict__ out_ll)
{
  __shared__ float la[64], wc[64];
  __shared__ float redm[4], reds[4];
  int tid = threadIdx.x;
  int b = blockIdx.x;
  if (tid < 64) la[tid] = logf(ah[(size_t)b*KK + tid]);
  else if (tid < 128 && b < T_LEN-1){
    int j = tid - 64;
    wc[j] = logB[(size_t)(b+1)*KK + j] + logf(bh[(size_t)(b+1)*KK + j]);
  }
  __syncthreads();
  if (tid < 64){
    float s = la[tid] + logf(bh[(size_t)b*KK + tid]);
    float m = wred_max(s);
    float p = (m < -3.0e37f) ? 1.f : expf(s - m);
    float ss = wred_sum(p);
    out_rhat[(size_t)b*KK + tid] = p/ss;
  }
  if (b == T_LEN-1){
    if (tid >= 64 && tid < 128){
      int i = tid - 64;
      float v = llp[i] + llp[i + 64];
      v = wred_sum(v);
      if (i == 0) out_ll[0] = v;
    }
    return;
  }
  int r = tid >> 6, j = tid & 63;
  float sv[16];
  float mx = -3.0e38f;
#pragma unroll
  for (int n = 0; n < 16; n++){
    int i = r + n*4;
    float s = la[i] + ElogA[i*KK + j] + wc[j];
    sv[n] = s;
    mx = fmaxf(mx, s);
  }
  float mxw = wred_max(mx);
  if ((tid & 63) == 0) redm[tid >> 6] = mxw;
  __syncthreads();
  float m = fmaxf(fmaxf(redm[0], redm[1]), fmaxf(redm[2], redm[3]));
  bool degen = !(m > -3.0e37f);
  float pv[16]; float ps = 0.f;
#pragma unroll
  for (int n = 0; n < 16; n++){
    float p = degen ? 1.f : expf(sv[n] - m);
    pv[n] = p; ps += p;
  }
  float psw = wred_sum(ps);
  if ((tid & 63) == 0) reds[tid >> 6] = psw;
  __syncthreads();
  float inv = 1.f/(reds[0] + reds[1] + reds[2] + reds[3]);
  float* dst = out_xi + (size_t)b*4096;
#pragma unroll
  for (int n = 0; n < 16; n++){
    int i = r + n*4;
    dst[i*KK + j] = pv[n]*inv;
  }
}

extern "C" void kernel_launch(void* const* d_in, const int* in_sizes, int n_in,
                              void* d_out, int out_size, void* d_ws, size_t ws_size,
                              hipStream_t stream)
{
  const float* mu    = (const float*)d_in[0];
  const float* dvar  = (const float*)d_in[1];
  const float* niwmu = (const float*)d_in[2];
  const float* Psi   = (const float*)d_in[3];
  const float* nu    = (const float*)d_in[4];
  const float* phi   = (const float*)d_in[5];
  const float* lpi   = (const float*)d_in[6];
  float* out = (float*)d_out;
  float* ws  = (float*)d_ws;

  size_t o = 0;
  float* EbfF   = ws + o; o += (size_t)DD*DD*KK/2;
  float* EdiagT = ws + o; o += (size_t)DD*KK;
  float* cvecT  = ws + o; o += (size_t)DD*KK;
  float* rK     = ws + o; o += KK;
  float* Lhalf  = ws + o; o += KK;
  float* sclK   = ws + o; o += KK;
  float* ElogA  = ws + o; o += KK*KK;
  float* P      = ws + o; o += KK*KK;
  float* PT     = ws + o; o += KK*KK;
  float* logB   = ws + o; o += (size_t)T_LEN*KK;
  float* mrowp  = ws + o; o += T_LEN;
  float* btil   = ws + o; o += (size_t)T_LEN*KK;
  float* G8     = ws + o; o += (size_t)1024*4096;
  float* H64    = ws + o; o += (size_t)128*4096;
  float* LH64   = ws + o; o += (size_t)128*4096;
  float* H128   = ws + o; o += (size_t)64*4096;
  float* HT128  = ws + o; o += (size_t)64*4096;
  float* aB     = ws + o; o += 64*64;
  float* bB     = ws + o; o += 64*64;
  float* llp    = ws + o; o += 128;
  float* ah     = ws + o; o += (size_t)T_LEN*KK;
  float* bh     = ws + o; o += (size_t)T_LEN*KK;
  if (ws_size < o*sizeof(float)) return;

  __bf16* Ebf = (__bf16*)EbfF;
  float*  part = G8;   // alias: consumed by k_logBall before k_pass1 writes G8

  hipFuncSetAttribute((const void*)k_neumann, hipFuncAttributeMaxDynamicSharedMemorySize, 2*DD*RS*4);
  hipFuncSetAttribute((const void*)k_logBall, hipFuncAttributeMaxDynamicSharedMemorySize, 2*DD*KK*4);

  k_neumann<<<64, 256, 2*DD*RS*4, stream>>>(Psi, niwmu, nu, phi, Ebf, EdiagT, cvecT, rK, Lhalf, sclK, ElogA, P, PT);
  k_q1<<<512, 256, 0, stream>>>(mu, Ebf, part);
  k_logBall<<<256, 256, 2*DD*KK*4, stream>>>(part, mu, dvar, cvecT, EdiagT, rK, Lhalf, sclK, logB, mrowp, btil);
  k_pass1<<<1024, 128, 0, stream>>>(P, btil, G8);
  k_chainM<<<128, 128, 0, stream>>>(G8, H64, LH64, nullptr, 8);
  k_chainM<<<64, 128, 0, stream>>>(H64, H128, nullptr, HT128, 2);
  k_pass2<<<2, 64, 0, stream>>>(H128, HT128, logB, lpi, aB, bB);
  k_pass3<<<256, 64, 0, stream>>>(P, PT, LH64, logB, mrowp, btil, lpi, aB, bB, ah, bh, llp);
  k_outs<<<T_LEN, 256, 0, stream>>>(ah, bh, ElogA, logB, llp, out, out + (size_t)T_LEN*KK,
                                    out + (size_t)T_LEN*KK + (size_t)(T_LEN-1)*KK*KK);
}